// Round 1
// 1302.792 us; speedup vs baseline: 1.0082x; 1.0082x over previous
//
#include <hip/hip_runtime.h>

#define D 128
#define SCAN_E 2048

typedef __attribute__((ext_vector_type(8))) short short8;
typedef __attribute__((ext_vector_type(4))) float floatx4;

__device__ __forceinline__ unsigned short f2bf(float x) {
    union { float f; unsigned u; } v; v.f = x;
    unsigned r = v.u + 0x7FFFu + ((v.u >> 16) & 1u);
    return (unsigned short)(r >> 16);
}
__device__ __forceinline__ float bf2f(unsigned short h) {
    union { float f; unsigned u; } v; v.u = ((unsigned)h) << 16;
    return v.f;
}
__device__ __forceinline__ void split2(float x, unsigned short& hi, unsigned short& lo) {
    hi = f2bf(x);
    lo = f2bf(x - bf2f(hi));
}
__device__ __forceinline__ void load16(const void* g, void* l) {
    __builtin_amdgcn_global_load_lds((const __attribute__((address_space(1))) unsigned*)g,
                                     (__attribute__((address_space(3))) unsigned*)l, 16, 0, 0);
}

// ---------- split-precision bf16 MFMA GEMM ----------
// C[M,NC] = A @ W^T (+bias) where A given as bf16 planes [M][256] = [Ah|Al] (fp32-split)
// and W given pre-split as [NC][384] = [Wh|Wh|Wl].  Effective K=384 bf16:
//   k in [0,128):  Ah*Wh ; [128,256): Al*Wh ; [256,384): Ah*Wl   (error <= 2^-17)
__global__ __launch_bounds__(256, 2)
void gemm_split(const unsigned short* __restrict__ Apl,
                const unsigned short* __restrict__ Wsp,
                const float* __restrict__ bias,
                float* __restrict__ Cf,            // fp32 out (or null)
                unsigned short* __restrict__ Cpl,  // bf16-plane out [M][256] (or null; NC==128 only)
                int M, int NC, int relu)
{
    __shared__ unsigned short sA[128 * 64];
    __shared__ unsigned short sW[128 * 64];
    const int t    = threadIdx.x;
    const int lane = t & 63;
    const int wv   = t >> 6;
    const int m0   = blockIdx.x * 128;
    const int n0   = blockIdx.y * 128;

    const int scolb = (lane & 7) * 16;     // byte offset within 128-B row chunk
    const int lrow  = lane >> 3;           // 0..7

    floatx4 acc[4][4];
    #pragma unroll
    for (int i = 0; i < 4; ++i)
        #pragma unroll
        for (int j = 0; j < 4; ++j)
            #pragma unroll
            for (int r = 0; r < 4; ++r) acc[i][j][r] = 0.f;

    for (int kk = 0; kk < 6; ++kk) {
        const int akb = ((kk < 4) ? kk : kk - 4) * 128;  // A-plane k-byte offset (row is 512 B)
        const int wkb = kk * 128;                        // W k-byte offset (row is 768 B)
        #pragma unroll
        for (int i = 0; i < 4; ++i) {
            const int rr = (wv * 4 + i) * 8 + lrow;      // 0..127 tile row
            int am = m0 + rr; if (am > M - 1) am = M - 1;
            load16((const char*)Apl + (size_t)am * 512 + akb + scolb,
                   (char*)sA + (size_t)(wv * 4 + i) * 1024);
            load16((const char*)Wsp + (size_t)(n0 + rr) * 768 + wkb + scolb,
                   (char*)sW + (size_t)(wv * 4 + i) * 1024);
        }
        __syncthreads();
        const int lane15 = lane & 15;
        const int quad   = lane >> 4;
        #pragma unroll
        for (int ks = 0; ks < 2; ++ks) {
            short8 a[4], b[4];
            const int koff = ks * 32 + quad * 8;
            #pragma unroll
            for (int i = 0; i < 4; ++i)
                a[i] = *(const short8*)(sA + ((wv >> 1) * 64 + i * 16 + lane15) * 64 + koff);
            #pragma unroll
            for (int j = 0; j < 4; ++j)
                b[j] = *(const short8*)(sW + ((wv & 1) * 64 + j * 16 + lane15) * 64 + koff);
            #pragma unroll
            for (int i = 0; i < 4; ++i)
                #pragma unroll
                for (int j = 0; j < 4; ++j)
                    acc[i][j] = __builtin_amdgcn_mfma_f32_16x16x32_bf16(a[i], b[j], acc[i][j], 0, 0, 0);
        }
        __syncthreads();
    }

    const int lane15 = lane & 15;
    const int quad   = lane >> 4;
    #pragma unroll
    for (int i = 0; i < 4; ++i) {
        #pragma unroll
        for (int r = 0; r < 4; ++r) {
            const int m = m0 + (wv >> 1) * 64 + i * 16 + quad * 4 + r;
            if (m >= M) continue;
            #pragma unroll
            for (int j = 0; j < 4; ++j) {
                const int n = n0 + (wv & 1) * 64 + j * 16 + lane15;
                float v = acc[i][j][r] + (bias ? bias[n] : 0.f);
                if (relu) v = fmaxf(v, 0.f);
                if (Cf) Cf[(size_t)m * NC + n] = v;
                if (Cpl) {
                    unsigned short hi, lo; split2(v, hi, lo);
                    Cpl[(size_t)m * 256 + n] = hi;
                    Cpl[(size_t)m * 256 + 128 + n] = lo;
                }
            }
        }
    }
}

// ---------- fused dual-GEMM + GRU ----------
// One block: 128 rows x 384 cols of BOTH  gi = Agg @ Wi^T  and  gh = H @ Wh^T
// (Wi = split(Wih@Wc) row-PERMUTED so each 96-col wave slice = 3 gates x 32 channels:
//  input row o=g*128+c stored at row' = (c/32)*96 + g*32 + (c%32)).
// Epilogue applies the GRU elementwise and updates h-planes IN PLACE (own rows only).
// 8 waves (2 row-halves x 4 col-quarters); acc = 2*24 frags = 192 VGPRs/wave.
// K-chunk = 32 keff (64 B/row) -> LDS row stride 64 B: the wave's ds_read_b128s map
// onto disjoint bank groups (no conflict beyond the b128 floor).
__global__ __launch_bounds__(512, 2)
void gru_gemm(const unsigned short* __restrict__ Apl,   // agg planes [N][256]
              unsigned short* __restrict__ Hpl,          // h planes [N][256], updated in place
              const unsigned short* __restrict__ Wi,     // split permuted fused Wih@Wc [384][384]
              const unsigned short* __restrict__ Wh,     // split permuted Whh        [384][384]
              const float* __restrict__ bih, const float* __restrict__ bhh,
              int M, int relu)
{
    __shared__ unsigned short sHa[128 * 32];
    __shared__ unsigned short sHh[128 * 32];
    __shared__ unsigned short sWi[384 * 32];
    __shared__ unsigned short sWh[384 * 32];
    const int t    = threadIdx.x;
    const int lane = t & 63;
    const int wv   = t >> 6;        // 0..7
    const int wr   = wv >> 2;       // 0..1 row half
    const int wc   = wv & 3;        // 0..3 col quarter (32 channels)
    const int m0   = blockIdx.x * 128;

    const int lrow  = lane >> 2;          // 0..15 (16 rows per load16 call)
    const int scolb = (lane & 3) * 16;    // byte offset in 64-B row chunk

    floatx4 ai[4][6], ah[4][6];
    #pragma unroll
    for (int i = 0; i < 4; ++i)
        #pragma unroll
        for (int j = 0; j < 6; ++j)
            #pragma unroll
            for (int r = 0; r < 4; ++r) { ai[i][j][r] = 0.f; ah[i][j][r] = 0.f; }

    const int lane15 = lane & 15;
    const int quad   = lane >> 4;
    const int koff   = quad * 8;

    for (int kk = 0; kk < 12; ++kk) {
        const int akb = ((kk < 8) ? kk : kk - 8) * 64;   // A row = 512 B: Ah,Al,Ah pattern
        const int wkb = kk * 64;                         // W row = 768 B: Wh,Wh,Wl
        if (wv == 0) {
            #pragma unroll
            for (int i = 0; i < 8; ++i) {
                int am = m0 + i * 16 + lrow; if (am > M - 1) am = M - 1;
                load16((const char*)Apl + (size_t)am * 512 + akb + scolb, (char*)sHa + i * 1024);
            }
        } else if (wv == 1) {
            #pragma unroll
            for (int i = 0; i < 8; ++i) {
                int am = m0 + i * 16 + lrow; if (am > M - 1) am = M - 1;
                load16((const char*)Hpl + (size_t)am * 512 + akb + scolb, (char*)sHh + i * 1024);
            }
        } else if (wv < 5) {
            #pragma unroll
            for (int i = 0; i < 8; ++i) {
                const int idx = (wv - 2) * 8 + i;        // 0..23 -> W rows idx*16..
                load16((const char*)Wi + (size_t)(idx * 16 + lrow) * 768 + wkb + scolb,
                       (char*)sWi + idx * 1024);
            }
        } else {
            #pragma unroll
            for (int i = 0; i < 8; ++i) {
                const int idx = (wv - 5) * 8 + i;
                load16((const char*)Wh + (size_t)(idx * 16 + lrow) * 768 + wkb + scolb,
                       (char*)sWh + idx * 1024);
            }
        }
        __syncthreads();
        short8 a_i[4], a_h[4];
        #pragma unroll
        for (int i = 0; i < 4; ++i) {
            const int row = wr * 64 + i * 16 + lane15;
            a_i[i] = *(const short8*)(sHa + row * 32 + koff);
            a_h[i] = *(const short8*)(sHh + row * 32 + koff);
        }
        #pragma unroll
        for (int j = 0; j < 6; ++j) {
            const int wrow = wc * 96 + j * 16 + lane15;
            const short8 b_i = *(const short8*)(sWi + wrow * 32 + koff);
            const short8 b_h = *(const short8*)(sWh + wrow * 32 + koff);
            #pragma unroll
            for (int i = 0; i < 4; ++i) {
                ai[i][j] = __builtin_amdgcn_mfma_f32_16x16x32_bf16(a_i[i], b_i, ai[i][j], 0, 0, 0);
                ah[i][j] = __builtin_amdgcn_mfma_f32_16x16x32_bf16(a_h[i], b_h, ah[i][j], 0, 0, 0);
            }
        }
        __syncthreads();
    }

    // frag j = 2*gate + ch  ->  gate = j>>1, channel c = wc*32 + (j&1)*16 + lane15
    float bi_[3][2], bh_[3][2];
    #pragma unroll
    for (int g = 0; g < 3; ++g)
        #pragma unroll
        for (int ch = 0; ch < 2; ++ch) {
            const int c = wc * 32 + ch * 16 + lane15;
            bi_[g][ch] = bih[g * 128 + c];
            bh_[g][ch] = bhh[g * 128 + c];
        }

    #pragma unroll
    for (int i = 0; i < 4; ++i) {
        #pragma unroll
        for (int r = 0; r < 4; ++r) {
            const int m = m0 + wr * 64 + i * 16 + quad * 4 + r;
            if (m >= M) continue;
            #pragma unroll
            for (int ch = 0; ch < 2; ++ch) {
                const int c  = wc * 32 + ch * 16 + lane15;
                const float rr  = ai[i][0 + ch][r] + bi_[0][ch] + ah[i][0 + ch][r] + bh_[0][ch];
                const float zz  = ai[i][2 + ch][r] + bi_[1][ch] + ah[i][2 + ch][r] + bh_[1][ch];
                const float in_ = ai[i][4 + ch][r] + bi_[2][ch];
                const float hn  = ah[i][4 + ch][r] + bh_[2][ch];
                const float rg = 1.f / (1.f + __expf(-rr));
                const float zg = 1.f / (1.f + __expf(-zz));
                const float ng = tanhf(in_ + rg * hn);
                const size_t hb = (size_t)m * 256 + c;
                const float hold = bf2f(Hpl[hb]) + bf2f(Hpl[hb + 128]);
                float v = (1.f - zg) * ng + zg * hold;
                if (relu) v = fmaxf(v, 0.f);
                unsigned short hi, lo; split2(v, hi, lo);
                Hpl[hb]       = hi;
                Hpl[hb + 128] = lo;
            }
        }
    }
}

// ---------- weight fuse: Wf[l] = Wih @ Wconv[l]  ([384,128] = [384,128]@[128,128]) ----------
__global__ __launch_bounds__(256)
void fuse_w(const float* __restrict__ Wih, const float* __restrict__ Wconv,
            float* __restrict__ Wf)
{
    const int l = blockIdx.y;
    const int o = blockIdx.x * 2 + (threadIdx.x >> 7);
    const int k = threadIdx.x & 127;
    const float* wih = Wih + (size_t)o * 128;
    const float* wcc = Wconv + (size_t)l * 16384 + k;
    float s = 0.f;
    #pragma unroll 8
    for (int j = 0; j < 128; ++j) s += wih[j] * wcc[(size_t)j * 128];
    Wf[(size_t)l * 49152 + (size_t)o * 128 + k] = s;
}

// ---------- weight / activation splitting ----------
__global__ __launch_bounds__(256)
void split_wt(const float* __restrict__ W, unsigned short* __restrict__ out, int total)
{
    const int tid = blockIdx.x * 256 + threadIdx.x;
    if (tid >= total) return;
    const int n = tid >> 7, k = tid & 127;
    unsigned short hi, lo; split2(W[tid], hi, lo);
    out[(size_t)n * 384 + k]       = hi;
    out[(size_t)n * 384 + 128 + k] = hi;
    out[(size_t)n * 384 + 256 + k] = lo;
}

// split with gate-interleave row permutation for the GRU GEMM (input [384][128])
__global__ __launch_bounds__(256)
void split_wt_g(const float* __restrict__ W, unsigned short* __restrict__ out)
{
    const int tid = blockIdx.x * 256 + threadIdx.x;    // over 384*128 exactly
    const int o = tid >> 7, k = tid & 127;
    const int g = o >> 7, c = o & 127;                 // gate, channel
    const int op = (c >> 5) * 96 + g * 32 + (c & 31);  // permuted row
    unsigned short hi, lo; split2(W[tid], hi, lo);
    out[(size_t)op * 384 + k]       = hi;
    out[(size_t)op * 384 + 128 + k] = hi;
    out[(size_t)op * 384 + 256 + k] = lo;
}

__global__ __launch_bounds__(256)
void split_act(const float* __restrict__ A, unsigned short* __restrict__ out, int total)
{
    const int tid = blockIdx.x * 256 + threadIdx.x;
    if (tid >= total) return;
    const int n = tid >> 7, k = tid & 127;
    unsigned short hi, lo; split2(A[tid], hi, lo);
    out[(size_t)n * 256 + k]       = hi;
    out[(size_t)n * 256 + 128 + k] = lo;
}

// ---------- CSR build ----------
__global__ __launch_bounds__(256)
void count_dst(const int* __restrict__ dst, int* __restrict__ counts, int E, int N)
{
    const int e = blockIdx.x * 256 + threadIdx.x;
    if (e >= E) return;
    const int d = dst[e];
    if ((unsigned)d < (unsigned)N) atomicAdd(&counts[d], 1);
}

__global__ __launch_bounds__(256)
void scan_block(const int* __restrict__ counts, int* __restrict__ rowptr,
                int* __restrict__ partials, int N)
{
    __shared__ int sT[256];
    const int t = threadIdx.x;
    const int base = blockIdx.x * SCAN_E + t * 8;
    int v[8]; int s = 0;
    #pragma unroll
    for (int i = 0; i < 8; ++i) {
        const int idx = base + i;
        v[i] = (idx < N) ? counts[idx] : 0;
        s += v[i];
    }
    sT[t] = s;
    __syncthreads();
    for (int off = 1; off < 256; off <<= 1) {
        int x = (t >= off) ? sT[t - off] : 0;
        __syncthreads();
        sT[t] += x;
        __syncthreads();
    }
    if (t == 255) partials[blockIdx.x] = sT[255];
    int run = sT[t] - s;
    #pragma unroll
    for (int i = 0; i < 8; ++i) {
        const int idx = base + i;
        if (idx < N) rowptr[idx] = run;
        run += v[i];
    }
}

__global__ void scan_partials(int* __restrict__ partials, int nb,
                              int* __restrict__ rowptr, int N)
{
    if (threadIdx.x == 0 && blockIdx.x == 0) {
        int run = 0;
        for (int i = 0; i < nb; ++i) { int c = partials[i]; partials[i] = run; run += c; }
        rowptr[N] = run;
    }
}

__global__ __launch_bounds__(256)
void add_offsets(int* __restrict__ rowptr, const int* __restrict__ partials,
                 int* __restrict__ cursor, int N)
{
    const int off  = partials[blockIdx.x];
    const int base = blockIdx.x * SCAN_E + threadIdx.x * 8;
    #pragma unroll
    for (int i = 0; i < 8; ++i) {
        const int idx = base + i;
        if (idx < N) { const int r = rowptr[idx] + off; rowptr[idx] = r; cursor[idx] = r; }
    }
}

__global__ __launch_bounds__(256)
void fill_csr(const int* __restrict__ src, const int* __restrict__ dst,
              int* __restrict__ cursor, int* __restrict__ eidx, int E, int N)
{
    const int e = blockIdx.x * 256 + threadIdx.x;
    if (e >= E) return;
    const int d = dst[e], s = src[e];
    if ((unsigned)d >= (unsigned)N || (unsigned)s >= (unsigned)N) return;
    const int slot = atomicAdd(&cursor[d], 1);
    eidx[slot] = s;
}

// ---------- gather directly on h planes: aggpl = planes(segment_sum(h[src])) ----------
__global__ __launch_bounds__(256)
void gather_sum_h(const unsigned short* __restrict__ hpl, const int* __restrict__ rowptr,
                  const int* __restrict__ eidx, unsigned short* __restrict__ aggpl, int N)
{
    const int tid  = blockIdx.x * 256 + threadIdx.x;
    const int node = tid >> 5;
    const int lane = tid & 31;
    if (node >= N) return;
    const int beg = rowptr[node];
    const int end = rowptr[node + 1];
    float4 acc = make_float4(0.f, 0.f, 0.f, 0.f);
    for (int e = beg; e < end; ++e) {
        const int s = eidx[e];
        const ushort4 vh = *reinterpret_cast<const ushort4*>(hpl + (size_t)s * 256 + lane * 4);
        const ushort4 vl = *reinterpret_cast<const ushort4*>(hpl + (size_t)s * 256 + 128 + lane * 4);
        acc.x += bf2f(vh.x) + bf2f(vl.x);
        acc.y += bf2f(vh.y) + bf2f(vl.y);
        acc.z += bf2f(vh.z) + bf2f(vl.z);
        acc.w += bf2f(vh.w) + bf2f(vl.w);
    }
    ushort4 hi, lo;
    split2(acc.x, hi.x, lo.x); split2(acc.y, hi.y, lo.y);
    split2(acc.z, hi.z, lo.z); split2(acc.w, hi.w, lo.w);
    *reinterpret_cast<ushort4*>(aggpl + (size_t)node * 256 + lane * 4)       = hi;
    *reinterpret_cast<ushort4*>(aggpl + (size_t)node * 256 + 128 + lane * 4) = lo;
}

extern "C" void kernel_launch(void* const* d_in, const int* in_sizes, int n_in,
                              void* d_out, int out_size, void* d_ws, size_t ws_size,
                              hipStream_t stream)
{
    const float* x     = (const float*)d_in[0];
    const int*   edges = (const int*)  d_in[1];
    const float* W1    = (const float*)d_in[2];
    const float* b1    = (const float*)d_in[3];
    const float* Wconv = (const float*)d_in[4];
    const float* Wih   = (const float*)d_in[5];
    const float* Whh   = (const float*)d_in[6];
    const float* bih   = (const float*)d_in[7];
    const float* bhh   = (const float*)d_in[8];
    const float* W2    = (const float*)d_in[9];
    const float* b2    = (const float*)d_in[10];
    float* out = (float*)d_out;

    const int N = in_sizes[0] / D;   // 100000
    const int E = in_sizes[1] / 2;   // 600000

    // ---- workspace layout (~108 MB) ----
    char* base = (char*)d_ws;
    const size_t szH = (size_t)N * 256 * 2;                       // 51.2 MB per plane buffer
    unsigned short* h_pl   = (unsigned short*)base;
    unsigned short* agg_pl = (unsigned short*)(base + szH);
    char* wb = base + 2 * szH;
    unsigned short* W1s  = (unsigned short*)wb;                   // 128*384
    unsigned short* W2s  = W1s  + (size_t)128 * 384;              // 384*384
    unsigned short* Whhs = W2s  + (size_t)384 * 384;              // 384*384 (permuted)
    unsigned short* Wfs  = Whhs + (size_t)384 * 384;              // 3 * 384*384 (permuted fused)
    float* Wfb = (float*)(Wfs + (size_t)3 * 384 * 384);           // 3*384*128 fp32 temp
    int* rowptr   = (int*)((char*)Wfb + (size_t)3 * 384 * 128 * 4);
    int* counts   = rowptr + N + 1;                               // doubles as cursor
    int* partials = counts + N;
    int* eidx     = partials + 64;
    unsigned short* x_pl = agg_pl;   // alias: x planes dead before first gather writes agg

    const int* src = edges;
    const int* dst = edges + E;

    const dim3 blk(256);
    const int mb = (N + 127) / 128;                 // 782
    const int nb = (N + SCAN_E - 1) / SCAN_E;

    // ---- weight prep ----
    split_wt<<<dim3(64),  blk, 0, stream>>>(W1, W1s, 128 * 128);
    split_wt<<<dim3(192), blk, 0, stream>>>(W2, W2s, 384 * 128);
    fuse_w<<<dim3(192, 3), blk, 0, stream>>>(Wih, Wconv, Wfb);
    for (int l = 0; l < 3; ++l)
        split_wt_g<<<dim3(192), blk, 0, stream>>>(Wfb + (size_t)l * 49152,
                                                  Wfs + (size_t)l * 147456);
    split_wt_g<<<dim3(192), blk, 0, stream>>>(Whh, Whhs);
    split_act<<<dim3((N * 128 + 255) / 256), blk, 0, stream>>>(x, x_pl, N * 128);

    // ---- build CSR (dst-bucketed) once ----
    hipMemsetAsync(counts, 0, (size_t)N * sizeof(int), stream);
    count_dst<<<dim3((E + 255) / 256), blk, 0, stream>>>(dst, counts, E, N);
    scan_block<<<dim3(nb), blk, 0, stream>>>(counts, rowptr, partials, N);
    scan_partials<<<dim3(1), dim3(64), 0, stream>>>(partials, nb, rowptr, N);
    add_offsets<<<dim3(nb), blk, 0, stream>>>(rowptr, partials, counts, N);
    fill_csr<<<dim3((E + 255) / 256), blk, 0, stream>>>(src, dst, counts, eidx, E, N);

    // ---- h = relu(x @ W1^T + b1), stored as planes only ----
    gemm_split<<<dim3(mb, 1), blk, 0, stream>>>(x_pl, W1s, b1, nullptr, h_pl, N, 128, 1);

    // ---- layers: gather(h) then fused dual-GEMM + GRU (in-place h update) ----
    for (int l = 0; l < 3; ++l) {
        gather_sum_h<<<dim3((N * 32 + 255) / 256), blk, 0, stream>>>(h_pl, rowptr, eidx, agg_pl, N);
        gru_gemm<<<dim3(mb), dim3(512), 0, stream>>>(agg_pl, h_pl,
                                                     Wfs + (size_t)l * 147456, Whhs,
                                                     bih, bhh, N, l == 2);
    }

    // ---- out = relu(h) @ W2^T + b2 (relu already applied in planes) ----
    gemm_split<<<dim3(mb, 3), blk, 0, stream>>>(h_pl, W2s, b2, out, nullptr, N, 384, 0);
}

// Round 2
// 1147.725 us; speedup vs baseline: 1.1444x; 1.1351x over previous
//
#include <hip/hip_runtime.h>

#define D 128
#define SCAN_E 2048

typedef __attribute__((ext_vector_type(8))) short short8;
typedef __attribute__((ext_vector_type(4))) float floatx4;

__device__ __forceinline__ unsigned short f2bf(float x) {
    union { float f; unsigned u; } v; v.f = x;
    unsigned r = v.u + 0x7FFFu + ((v.u >> 16) & 1u);
    return (unsigned short)(r >> 16);
}
__device__ __forceinline__ float bf2f(unsigned short h) {
    union { float f; unsigned u; } v; v.u = ((unsigned)h) << 16;
    return v.f;
}
__device__ __forceinline__ void split2(float x, unsigned short& hi, unsigned short& lo) {
    hi = f2bf(x);
    lo = f2bf(x - bf2f(hi));
}
__device__ __forceinline__ void load16(const void* g, void* l) {
    __builtin_amdgcn_global_load_lds((const __attribute__((address_space(1))) unsigned*)g,
                                     (__attribute__((address_space(3))) unsigned*)l, 16, 0, 0);
}

// ---------- split-precision bf16 MFMA GEMM ----------
// C[M,NC] = A @ W^T (+bias); A as bf16 planes [M][256] = [Ah|Al], W as [NC][256] = [Wh|Wl].
// Effective K=384 bf16: Ah*Wh ; Al*Wh ; Ah*Wl  (error <= 2^-17).
__global__ __launch_bounds__(256, 2)
void gemm_split(const unsigned short* __restrict__ Apl,
                const unsigned short* __restrict__ Wsp,
                const float* __restrict__ bias,
                float* __restrict__ Cf,            // fp32 out (or null)
                unsigned short* __restrict__ Cpl,  // bf16-plane out [M][256] (or null; NC==128 only)
                int M, int NC, int relu)
{
    __shared__ unsigned short sA[128 * 64];
    __shared__ unsigned short sW[128 * 64];
    const int t    = threadIdx.x;
    const int lane = t & 63;
    const int wv   = t >> 6;
    const int m0   = blockIdx.x * 128;
    const int n0   = blockIdx.y * 128;

    const int scolb = (lane & 7) * 16;     // byte offset within 128-B row chunk
    const int lrow  = lane >> 3;           // 0..7

    floatx4 acc[4][4];
    #pragma unroll
    for (int i = 0; i < 4; ++i)
        #pragma unroll
        for (int j = 0; j < 4; ++j)
            #pragma unroll
            for (int r = 0; r < 4; ++r) acc[i][j][r] = 0.f;

    for (int kk = 0; kk < 6; ++kk) {
        const int akb = ((kk < 4) ? kk : kk - 4) * 128;  // A row = 512 B: Ah,Al,Ah
        const int wkb = ((kk < 2) ? kk : kk - 2) * 128;  // W row = 512 B: Wh,Wh,Wl
        #pragma unroll
        for (int i = 0; i < 4; ++i) {
            const int rr = (wv * 4 + i) * 8 + lrow;      // 0..127 tile row
            int am = m0 + rr; if (am > M - 1) am = M - 1;
            load16((const char*)Apl + (size_t)am * 512 + akb + scolb,
                   (char*)sA + (size_t)(wv * 4 + i) * 1024);
            load16((const char*)Wsp + (size_t)(n0 + rr) * 512 + wkb + scolb,
                   (char*)sW + (size_t)(wv * 4 + i) * 1024);
        }
        __syncthreads();
        const int lane15 = lane & 15;
        const int quad   = lane >> 4;
        #pragma unroll
        for (int ks = 0; ks < 2; ++ks) {
            short8 a[4], b[4];
            const int koff = ks * 32 + quad * 8;
            #pragma unroll
            for (int i = 0; i < 4; ++i)
                a[i] = *(const short8*)(sA + ((wv >> 1) * 64 + i * 16 + lane15) * 64 + koff);
            #pragma unroll
            for (int j = 0; j < 4; ++j)
                b[j] = *(const short8*)(sW + ((wv & 1) * 64 + j * 16 + lane15) * 64 + koff);
            #pragma unroll
            for (int i = 0; i < 4; ++i)
                #pragma unroll
                for (int j = 0; j < 4; ++j)
                    acc[i][j] = __builtin_amdgcn_mfma_f32_16x16x32_bf16(a[i], b[j], acc[i][j], 0, 0, 0);
        }
        __syncthreads();
    }

    const int lane15 = lane & 15;
    const int quad   = lane >> 4;
    #pragma unroll
    for (int i = 0; i < 4; ++i) {
        #pragma unroll
        for (int r = 0; r < 4; ++r) {
            const int m = m0 + (wv >> 1) * 64 + i * 16 + quad * 4 + r;
            if (m >= M) continue;
            #pragma unroll
            for (int j = 0; j < 4; ++j) {
                const int n = n0 + (wv & 1) * 64 + j * 16 + lane15;
                float v = acc[i][j][r] + (bias ? bias[n] : 0.f);
                if (relu) v = fmaxf(v, 0.f);
                if (Cf) Cf[(size_t)m * NC + n] = v;
                if (Cpl) {
                    unsigned short hi, lo; split2(v, hi, lo);
                    Cpl[(size_t)m * 256 + n] = hi;
                    Cpl[(size_t)m * 256 + 128 + n] = lo;
                }
            }
        }
    }
}

// ---------- fused dual-GEMM + GRU (gate-merged acc, double-buffered) ----------
// One block: 128 rows x 384 cols of BOTH gi = Agg @ Wi^T and gh = H @ Wh^T.
// W row-PERMUTED so each 96-col wave slice = [r(32) | z(32) | n(32)] of the same channels.
// r,z gates only need gi+gh -> their fragments are accumulated SHARED across both GEMMs
// (exact: same fp32 accumulation, re-associated). Only n keeps in/hn separate.
// Acc/wave: 16 (rz) + 8 (in) + 8 (hn) = 32 frags = 128 regs -> no spill at 256-reg budget.
// LDS: 2 x 64 KB double buffer; per chunk issue next-chunk global_load_lds BEFORE the
// ds_read+MFMA of the current chunk; single barrier per chunk (2-phase schedule).
__device__ __forceinline__ void gg_stage(unsigned short* L,
    const unsigned short* Apl, const unsigned short* Hpl,
    const unsigned short* Wi, const unsigned short* Wh,
    int wv, int lrow, int scolb, int m0, int M, int kk)
{
    const int akb = ((kk < 8) ? kk : kk - 8) * 64;   // A row = 512 B: Ah(0-3),Al(4-7),Ah(8-11)
    const int wkb = ((kk < 4) ? kk : kk - 4) * 64;   // W row = 512 B: Wh(0-3),Wh(4-7),Wl(8-11)
    if (wv == 0) {
        #pragma unroll
        for (int i = 0; i < 8; ++i) {
            int am = m0 + i * 16 + lrow; if (am > M - 1) am = M - 1;
            load16((const char*)Apl + (size_t)am * 512 + akb + scolb, (char*)L + i * 1024);
        }
    } else if (wv == 1) {
        #pragma unroll
        for (int i = 0; i < 8; ++i) {
            int am = m0 + i * 16 + lrow; if (am > M - 1) am = M - 1;
            load16((const char*)Hpl + (size_t)am * 512 + akb + scolb, (char*)L + 8192 + i * 1024);
        }
    } else if (wv < 5) {
        #pragma unroll
        for (int i = 0; i < 8; ++i) {
            const int idx = (wv - 2) * 8 + i;        // 0..23
            load16((const char*)Wi + (size_t)(idx * 16 + lrow) * 512 + wkb + scolb,
                   (char*)L + 16384 + idx * 1024);
        }
    } else {
        #pragma unroll
        for (int i = 0; i < 8; ++i) {
            const int idx = (wv - 5) * 8 + i;
            load16((const char*)Wh + (size_t)(idx * 16 + lrow) * 512 + wkb + scolb,
                   (char*)L + 40960 + idx * 1024);
        }
    }
}

__global__ __launch_bounds__(512, 2)
void gru_gemm(const unsigned short* __restrict__ Apl,   // agg planes [N][256]
              unsigned short* __restrict__ Hpl,          // h planes [N][256], updated in place
              const unsigned short* __restrict__ Wi,     // split permuted fused Wih@Wc [384][256]
              const unsigned short* __restrict__ Wh,     // split permuted Whh        [384][256]
              const float* __restrict__ bih, const float* __restrict__ bhh,
              int M, int relu)
{
    __shared__ unsigned short lds[2][32768];   // 2 x 64 KB: sHa(8K) | sHh(8K) | sWi(24K) | sWh(24K)
    const int t    = threadIdx.x;
    const int lane = t & 63;
    const int wv   = t >> 6;        // 0..7
    const int wr   = wv >> 2;       // 0..1 row half
    const int wc   = wv & 3;        // 0..3 col quarter (32 channels)
    const int m0   = blockIdx.x * 128;

    const int lrow  = lane >> 2;          // 0..15
    const int scolb = (lane & 3) * 16;    // byte offset in 64-B row chunk

    floatx4 arz[4][4], ain[4][2], ahn[4][2];
    #pragma unroll
    for (int i = 0; i < 4; ++i) {
        #pragma unroll
        for (int j = 0; j < 4; ++j)
            #pragma unroll
            for (int r = 0; r < 4; ++r) arz[i][j][r] = 0.f;
        #pragma unroll
        for (int j = 0; j < 2; ++j)
            #pragma unroll
            for (int r = 0; r < 4; ++r) { ain[i][j][r] = 0.f; ahn[i][j][r] = 0.f; }
    }

    const int lane15 = lane & 15;
    const int quad   = lane >> 4;
    const int koff   = quad * 8;

    gg_stage(&lds[0][0], Apl, Hpl, Wi, Wh, wv, lrow, scolb, m0, M, 0);
    __syncthreads();   // implies vmcnt(0) drain of the staged chunk

    int cur = 0;
    for (int kk = 0; kk < 12; ++kk) {
        if (kk < 11)
            gg_stage(&lds[cur ^ 1][0], Apl, Hpl, Wi, Wh, wv, lrow, scolb, m0, M, kk + 1);
        const unsigned short* B = &lds[cur][0];
        short8 a_i[4], a_h[4];
        #pragma unroll
        for (int i = 0; i < 4; ++i) {
            const int row = wr * 64 + i * 16 + lane15;
            a_i[i] = *(const short8*)(B + row * 32 + koff);
            a_h[i] = *(const short8*)(B + 4096 + row * 32 + koff);
        }
        #pragma unroll
        for (int j = 0; j < 6; ++j) {
            const int wrow = wc * 96 + j * 16 + lane15;
            const short8 b_i = *(const short8*)(B + 8192 + wrow * 32 + koff);
            const short8 b_h = *(const short8*)(B + 20480 + wrow * 32 + koff);
            if (j < 4) {
                #pragma unroll
                for (int i = 0; i < 4; ++i) {
                    arz[i][j] = __builtin_amdgcn_mfma_f32_16x16x32_bf16(a_i[i], b_i, arz[i][j], 0, 0, 0);
                    arz[i][j] = __builtin_amdgcn_mfma_f32_16x16x32_bf16(a_h[i], b_h, arz[i][j], 0, 0, 0);
                }
            } else {
                #pragma unroll
                for (int i = 0; i < 4; ++i) {
                    ain[i][j - 4] = __builtin_amdgcn_mfma_f32_16x16x32_bf16(a_i[i], b_i, ain[i][j - 4], 0, 0, 0);
                    ahn[i][j - 4] = __builtin_amdgcn_mfma_f32_16x16x32_bf16(a_h[i], b_h, ahn[i][j - 4], 0, 0, 0);
                }
            }
        }
        __syncthreads();   // drains vmcnt(0): next chunk staged; also guards buffer reuse
        cur ^= 1;
    }

    // frag j = 2*gate + ch for r,z ; ain/ahn[.][ch] for n.  channel c = wc*32 + ch*16 + lane15
    float bi_[3][2], bh_[3][2];
    #pragma unroll
    for (int g = 0; g < 3; ++g)
        #pragma unroll
        for (int ch = 0; ch < 2; ++ch) {
            const int c = wc * 32 + ch * 16 + lane15;
            bi_[g][ch] = bih[g * 128 + c];
            bh_[g][ch] = bhh[g * 128 + c];
        }

    #pragma unroll
    for (int i = 0; i < 4; ++i) {
        #pragma unroll
        for (int r = 0; r < 4; ++r) {
            const int m = m0 + wr * 64 + i * 16 + quad * 4 + r;
            if (m >= M) continue;
            #pragma unroll
            for (int ch = 0; ch < 2; ++ch) {
                const int c  = wc * 32 + ch * 16 + lane15;
                const float rr  = arz[i][0 + ch][r] + bi_[0][ch] + bh_[0][ch];
                const float zz  = arz[i][2 + ch][r] + bi_[1][ch] + bh_[1][ch];
                const float in_ = ain[i][ch][r] + bi_[2][ch];
                const float hn  = ahn[i][ch][r] + bh_[2][ch];
                const float rg = 1.f / (1.f + __expf(-rr));
                const float zg = 1.f / (1.f + __expf(-zz));
                const float ng = tanhf(in_ + rg * hn);
                const size_t hb = (size_t)m * 256 + c;
                const float hold = bf2f(Hpl[hb]) + bf2f(Hpl[hb + 128]);
                float v = (1.f - zg) * ng + zg * hold;
                if (relu) v = fmaxf(v, 0.f);
                unsigned short hi, lo; split2(v, hi, lo);
                Hpl[hb]       = hi;
                Hpl[hb + 128] = lo;
            }
        }
    }
}

// ---------- weight fuse: Wf[l] = Wih @ Wconv[l]  ([384,128] = [384,128]@[128,128]) ----------
__global__ __launch_bounds__(256)
void fuse_w(const float* __restrict__ Wih, const float* __restrict__ Wconv,
            float* __restrict__ Wf)
{
    const int l = blockIdx.y;
    const int o = blockIdx.x * 2 + (threadIdx.x >> 7);
    const int k = threadIdx.x & 127;
    const float* wih = Wih + (size_t)o * 128;
    const float* wcc = Wconv + (size_t)l * 16384 + k;
    float s = 0.f;
    #pragma unroll 8
    for (int j = 0; j < 128; ++j) s += wih[j] * wcc[(size_t)j * 128];
    Wf[(size_t)l * 49152 + (size_t)o * 128 + k] = s;
}

// ---------- splitting: rows of 128 fp32 -> [hi|lo] planes (256 shorts/row) ----------
__global__ __launch_bounds__(256)
void split_act(const float* __restrict__ A, unsigned short* __restrict__ out, int total)
{
    const int tid = blockIdx.x * 256 + threadIdx.x;
    if (tid >= total) return;
    const int n = tid >> 7, k = tid & 127;
    unsigned short hi, lo; split2(A[tid], hi, lo);
    out[(size_t)n * 256 + k]       = hi;
    out[(size_t)n * 256 + 128 + k] = lo;
}

// split with gate-interleave row permutation for the GRU GEMM (input [384][128])
__global__ __launch_bounds__(256)
void split_wt_g(const float* __restrict__ W, unsigned short* __restrict__ out)
{
    const int tid = blockIdx.x * 256 + threadIdx.x;    // over 384*128 exactly
    const int o = tid >> 7, k = tid & 127;
    const int g = o >> 7, c = o & 127;                 // gate, channel
    const int op = (c >> 5) * 96 + g * 32 + (c & 31);  // permuted row
    unsigned short hi, lo; split2(W[tid], hi, lo);
    out[(size_t)op * 256 + k]       = hi;
    out[(size_t)op * 256 + 128 + k] = lo;
}

// ---------- CSR build ----------
__global__ __launch_bounds__(256)
void count_dst(const int* __restrict__ dst, int* __restrict__ counts, int E, int N)
{
    const int e = blockIdx.x * 256 + threadIdx.x;
    if (e >= E) return;
    const int d = dst[e];
    if ((unsigned)d < (unsigned)N) atomicAdd(&counts[d], 1);
}

__global__ __launch_bounds__(256)
void scan_block(const int* __restrict__ counts, int* __restrict__ rowptr,
                int* __restrict__ partials, int N)
{
    __shared__ int sT[256];
    const int t = threadIdx.x;
    const int base = blockIdx.x * SCAN_E + t * 8;
    int v[8]; int s = 0;
    #pragma unroll
    for (int i = 0; i < 8; ++i) {
        const int idx = base + i;
        v[i] = (idx < N) ? counts[idx] : 0;
        s += v[i];
    }
    sT[t] = s;
    __syncthreads();
    for (int off = 1; off < 256; off <<= 1) {
        int x = (t >= off) ? sT[t - off] : 0;
        __syncthreads();
        sT[t] += x;
        __syncthreads();
    }
    if (t == 255) partials[blockIdx.x] = sT[255];
    int run = sT[t] - s;
    #pragma unroll
    for (int i = 0; i < 8; ++i) {
        const int idx = base + i;
        if (idx < N) rowptr[idx] = run;
        run += v[i];
    }
}

__global__ void scan_partials(int* __restrict__ partials, int nb,
                              int* __restrict__ rowptr, int N)
{
    if (threadIdx.x == 0 && blockIdx.x == 0) {
        int run = 0;
        for (int i = 0; i < nb; ++i) { int c = partials[i]; partials[i] = run; run += c; }
        rowptr[N] = run;
    }
}

__global__ __launch_bounds__(256)
void add_offsets(int* __restrict__ rowptr, const int* __restrict__ partials,
                 int* __restrict__ cursor, int N)
{
    const int off  = partials[blockIdx.x];
    const int base = blockIdx.x * SCAN_E + threadIdx.x * 8;
    #pragma unroll
    for (int i = 0; i < 8; ++i) {
        const int idx = base + i;
        if (idx < N) { const int r = rowptr[idx] + off; rowptr[idx] = r; cursor[idx] = r; }
    }
}

__global__ __launch_bounds__(256)
void fill_csr(const int* __restrict__ src, const int* __restrict__ dst,
              int* __restrict__ cursor, int* __restrict__ eidx, int E, int N)
{
    const int e = blockIdx.x * 256 + threadIdx.x;
    if (e >= E) return;
    const int d = dst[e], s = src[e];
    if ((unsigned)d >= (unsigned)N || (unsigned)s >= (unsigned)N) return;
    const int slot = atomicAdd(&cursor[d], 1);
    eidx[slot] = s;
}

// ---------- gather directly on h planes: aggpl = planes(segment_sum(h[src])) ----------
__global__ __launch_bounds__(256)
void gather_sum_h(const unsigned short* __restrict__ hpl, const int* __restrict__ rowptr,
                  const int* __restrict__ eidx, unsigned short* __restrict__ aggpl, int N)
{
    const int tid  = blockIdx.x * 256 + threadIdx.x;
    const int node = tid >> 5;
    const int lane = tid & 31;
    if (node >= N) return;
    const int beg = rowptr[node];
    const int end = rowptr[node + 1];
    float4 acc = make_float4(0.f, 0.f, 0.f, 0.f);
    for (int e = beg; e < end; ++e) {
        const int s = eidx[e];
        const ushort4 vh = *reinterpret_cast<const ushort4*>(hpl + (size_t)s * 256 + lane * 4);
        const ushort4 vl = *reinterpret_cast<const ushort4*>(hpl + (size_t)s * 256 + 128 + lane * 4);
        acc.x += bf2f(vh.x) + bf2f(vl.x);
        acc.y += bf2f(vh.y) + bf2f(vl.y);
        acc.z += bf2f(vh.z) + bf2f(vl.z);
        acc.w += bf2f(vh.w) + bf2f(vl.w);
    }
    ushort4 hi, lo;
    split2(acc.x, hi.x, lo.x); split2(acc.y, hi.y, lo.y);
    split2(acc.z, hi.z, lo.z); split2(acc.w, hi.w, lo.w);
    *reinterpret_cast<ushort4*>(aggpl + (size_t)node * 256 + lane * 4)       = hi;
    *reinterpret_cast<ushort4*>(aggpl + (size_t)node * 256 + 128 + lane * 4) = lo;
}

extern "C" void kernel_launch(void* const* d_in, const int* in_sizes, int n_in,
                              void* d_out, int out_size, void* d_ws, size_t ws_size,
                              hipStream_t stream)
{
    const float* x     = (const float*)d_in[0];
    const int*   edges = (const int*)  d_in[1];
    const float* W1    = (const float*)d_in[2];
    const float* b1    = (const float*)d_in[3];
    const float* Wconv = (const float*)d_in[4];
    const float* Wih   = (const float*)d_in[5];
    const float* Whh   = (const float*)d_in[6];
    const float* bih   = (const float*)d_in[7];
    const float* bhh   = (const float*)d_in[8];
    const float* W2    = (const float*)d_in[9];
    const float* b2    = (const float*)d_in[10];
    float* out = (float*)d_out;

    const int N = in_sizes[0] / D;   // 100000
    const int E = in_sizes[1] / 2;   // 600000

    // ---- workspace layout (~107 MB) ----
    char* base = (char*)d_ws;
    const size_t szH = (size_t)N * 256 * 2;                       // 51.2 MB per plane buffer
    unsigned short* h_pl   = (unsigned short*)base;
    unsigned short* agg_pl = (unsigned short*)(base + szH);
    char* wb = base + 2 * szH;
    unsigned short* W1s  = (unsigned short*)wb;                   // 128*256
    unsigned short* W2s  = W1s  + (size_t)128 * 256;              // 384*256
    unsigned short* Whhs = W2s  + (size_t)384 * 256;              // 384*256 (permuted)
    unsigned short* Wfs  = Whhs + (size_t)384 * 256;              // 3 * 384*256 (permuted fused)
    float* Wfb = (float*)(Wfs + (size_t)3 * 384 * 256);           // 3*384*128 fp32 temp
    int* rowptr   = (int*)((char*)Wfb + (size_t)3 * 384 * 128 * 4);
    int* counts   = rowptr + N + 1;                               // doubles as cursor
    int* partials = counts + N;
    int* eidx     = partials + 64;
    unsigned short* x_pl = agg_pl;   // alias: x planes dead before first gather writes agg

    const int* src = edges;
    const int* dst = edges + E;

    const dim3 blk(256);
    const int mb = (N + 127) / 128;                 // 782
    const int nb = (N + SCAN_E - 1) / SCAN_E;

    // ---- weight prep ----
    split_act<<<dim3(64),  blk, 0, stream>>>(W1, W1s, 128 * 128);
    split_act<<<dim3(192), blk, 0, stream>>>(W2, W2s, 384 * 128);
    fuse_w<<<dim3(192, 3), blk, 0, stream>>>(Wih, Wconv, Wfb);
    for (int l = 0; l < 3; ++l)
        split_wt_g<<<dim3(192), blk, 0, stream>>>(Wfb + (size_t)l * 49152,
                                                  Wfs + (size_t)l * 98304);
    split_wt_g<<<dim3(192), blk, 0, stream>>>(Whh, Whhs);
    split_act<<<dim3((N * 128 + 255) / 256), blk, 0, stream>>>(x, x_pl, N * 128);

    // ---- build CSR (dst-bucketed) once ----
    hipMemsetAsync(counts, 0, (size_t)N * sizeof(int), stream);
    count_dst<<<dim3((E + 255) / 256), blk, 0, stream>>>(dst, counts, E, N);
    scan_block<<<dim3(nb), blk, 0, stream>>>(counts, rowptr, partials, N);
    scan_partials<<<dim3(1), dim3(64), 0, stream>>>(partials, nb, rowptr, N);
    add_offsets<<<dim3(nb), blk, 0, stream>>>(rowptr, partials, counts, N);
    fill_csr<<<dim3((E + 255) / 256), blk, 0, stream>>>(src, dst, counts, eidx, E, N);

    // ---- h = relu(x @ W1^T + b1), stored as planes only ----
    gemm_split<<<dim3(mb, 1), blk, 0, stream>>>(x_pl, W1s, b1, nullptr, h_pl, N, 128, 1);

    // ---- layers: gather(h) then fused dual-GEMM + GRU (in-place h update) ----
    for (int l = 0; l < 3; ++l) {
        gather_sum_h<<<dim3((N * 32 + 255) / 256), blk, 0, stream>>>(h_pl, rowptr, eidx, agg_pl, N);
        gru_gemm<<<dim3(mb), dim3(512), 0, stream>>>(agg_pl, h_pl,
                                                     Wfs + (size_t)l * 98304, Whhs,
                                                     bih, bhh, N, l == 2);
    }

    // ---- out = relu(h) @ W2^T + b2 (relu already applied in planes) ----
    gemm_split<<<dim3(mb, 3), blk, 0, stream>>>(h_pl, W2s, b2, out, nullptr, N, 384, 0);
}

// Round 3
// 954.234 us; speedup vs baseline: 1.3764x; 1.2028x over previous
//
#include <hip/hip_runtime.h>

#define D 128
#define SCAN_E 2048

typedef __attribute__((ext_vector_type(8))) short short8;
typedef __attribute__((ext_vector_type(8))) unsigned short ushort8v;
typedef __attribute__((ext_vector_type(4))) float floatx4;

__device__ __forceinline__ unsigned short f2bf(float x) {
    union { float f; unsigned u; } v; v.f = x;
    unsigned r = v.u + 0x7FFFu + ((v.u >> 16) & 1u);
    return (unsigned short)(r >> 16);
}
__device__ __forceinline__ float bf2f(unsigned short h) {
    union { float f; unsigned u; } v; v.u = ((unsigned)h) << 16;
    return v.f;
}
__device__ __forceinline__ void split2(float x, unsigned short& hi, unsigned short& lo) {
    hi = f2bf(x);
    lo = f2bf(x - bf2f(hi));
}
__device__ __forceinline__ void load16(const void* g, void* l) {
    __builtin_amdgcn_global_load_lds((const __attribute__((address_space(1))) unsigned*)g,
                                     (__attribute__((address_space(3))) unsigned*)l, 16, 0, 0);
}

// ---------- split-precision bf16 MFMA GEMM ----------
// C[M,NC] = A @ W^T (+bias); A as bf16 planes [M][256] = [Ah|Al], W as [NC][256] = [Wh|Wl].
// Effective K=384 bf16: Ah*Wh ; Al*Wh ; Ah*Wl  (error <= 2^-17).
// XOR source-pre-swizzle on staging + matching ds_read slot swizzle (bank-conflict fix).
__global__ __launch_bounds__(256, 2)
void gemm_split(const unsigned short* __restrict__ Apl,
                const unsigned short* __restrict__ Wsp,
                const float* __restrict__ bias,
                float* __restrict__ Cf,            // fp32 out (or null)
                unsigned short* __restrict__ Cpl,  // bf16-plane out [M][256] (or null; NC==128 only)
                int M, int NC, int relu)
{
    __shared__ unsigned short sA[128 * 64];
    __shared__ unsigned short sW[128 * 64];
    const int t    = threadIdx.x;
    const int lane = t & 63;
    const int wv   = t >> 6;
    const int m0   = blockIdx.x * 128;
    const int n0   = blockIdx.y * 128;

    const int lrow  = lane >> 3;                         // 0..7
    const int scolb = (((lane & 7) ^ (lrow & 7)) << 4);  // pre-swizzled 16-B slot

    floatx4 acc[4][4];
    #pragma unroll
    for (int i = 0; i < 4; ++i)
        #pragma unroll
        for (int j = 0; j < 4; ++j)
            #pragma unroll
            for (int r = 0; r < 4; ++r) acc[i][j][r] = 0.f;

    for (int kk = 0; kk < 6; ++kk) {
        const int akb = ((kk < 4) ? kk : kk - 4) * 128;  // A row = 512 B: Ah,Al,Ah
        const int wkb = ((kk < 2) ? kk : kk - 2) * 128;  // W row = 512 B: Wh,Wh,Wl
        #pragma unroll
        for (int i = 0; i < 4; ++i) {
            const int rr = (wv * 4 + i) * 8 + lrow;      // 0..127 tile row
            int am = m0 + rr; if (am > M - 1) am = M - 1;
            load16((const char*)Apl + (size_t)am * 512 + akb + scolb,
                   (char*)sA + (size_t)(wv * 4 + i) * 1024);
            load16((const char*)Wsp + (size_t)(n0 + rr) * 512 + wkb + scolb,
                   (char*)sW + (size_t)(wv * 4 + i) * 1024);
        }
        __syncthreads();
        const int lane15 = lane & 15;
        const int quad   = lane >> 4;
        const int r7     = lane15 & 7;
        #pragma unroll
        for (int ks = 0; ks < 2; ++ks) {
            short8 a[4], b[4];
            const int sl = ((ks * 4 + quad) ^ r7) * 8;   // swizzled 8-short slot
            #pragma unroll
            for (int i = 0; i < 4; ++i)
                a[i] = *(const short8*)(sA + ((wv >> 1) * 64 + i * 16 + lane15) * 64 + sl);
            #pragma unroll
            for (int j = 0; j < 4; ++j)
                b[j] = *(const short8*)(sW + ((wv & 1) * 64 + j * 16 + lane15) * 64 + sl);
            #pragma unroll
            for (int i = 0; i < 4; ++i)
                #pragma unroll
                for (int j = 0; j < 4; ++j)
                    acc[i][j] = __builtin_amdgcn_mfma_f32_16x16x32_bf16(a[i], b[j], acc[i][j], 0, 0, 0);
        }
        __syncthreads();
    }

    const int lane15 = lane & 15;
    const int quad   = lane >> 4;
    #pragma unroll
    for (int i = 0; i < 4; ++i) {
        #pragma unroll
        for (int r = 0; r < 4; ++r) {
            const int m = m0 + (wv >> 1) * 64 + i * 16 + quad * 4 + r;
            if (m >= M) continue;
            #pragma unroll
            for (int j = 0; j < 4; ++j) {
                const int n = n0 + (wv & 1) * 64 + j * 16 + lane15;
                float v = acc[i][j][r] + (bias ? bias[n] : 0.f);
                if (relu) v = fmaxf(v, 0.f);
                if (Cf) Cf[(size_t)m * NC + n] = v;
                if (Cpl) {
                    unsigned short hi, lo; split2(v, hi, lo);
                    Cpl[(size_t)m * 256 + n] = hi;
                    Cpl[(size_t)m * 256 + 128 + n] = lo;
                }
            }
        }
    }
}

// ---------- fused dual-GEMM + GRU, column-split, 64-row tile ----------
// grid (ceil(N/64), 2). Block: 256 thr (4 waves), 64 rows x 64 channels (col-half h).
// Per wave (wc): 16 channels = permuted W rows [wc*48, wc*48+48) of the half's 192 rows:
// [r(16)|z(16)|n(16)].  r,z fragments accumulate BOTH GEMMs (gi+gh, exact).
// LDS: 2 x 32 KB dbuf -> 64 KB/block -> 2 blocks/CU (barrier-drain overlap across blocks).
// h ping-pong (Hcur -> Hnxt) since column-halves of a row are different blocks.
// Epilogue: hold staged to LDS via global_load_lds (hidden under last chunk), coalesced
// full-row writeback.
__device__ __forceinline__ void gg_stage(unsigned short* L,
    const unsigned short* Apl, const unsigned short* Hpl,
    const unsigned short* Wi, const unsigned short* Wh,
    int wv, int lane, int m0, int M, int h, int kk)
{
    const int lrow  = lane >> 2;                          // 0..15
    const int scolb = (((lane & 3) ^ (lrow & 3)) << 4);   // pre-swizzled 16-B slot
    const int akb = ((kk < 8) ? kk : kk - 8) * 64;        // A row 512 B: Ah,Al,Ah
    const int wkb = ((kk < 4) ? kk : kk - 4) * 64;        // W row 512 B: Wh,Wh,Wl
    #pragma unroll
    for (int i = 0; i < 8; ++i) {
        const int s = wv * 8 + i;                          // 0..31, wave-uniform per instr
        const char* src; char* dst;
        if (s < 4) {
            int am = m0 + s * 16 + lrow; if (am > M - 1) am = M - 1;
            src = (const char*)Apl + (size_t)am * 512 + akb + scolb;
            dst = (char*)L + s * 1024;
        } else if (s < 8) {
            int am = m0 + (s - 4) * 16 + lrow; if (am > M - 1) am = M - 1;
            src = (const char*)Hpl + (size_t)am * 512 + akb + scolb;
            dst = (char*)L + 4096 + (s - 4) * 1024;
        } else if (s < 20) {
            src = (const char*)Wi + (size_t)(h * 192 + (s - 8) * 16 + lrow) * 512 + wkb + scolb;
            dst = (char*)L + 8192 + (s - 8) * 1024;
        } else {
            src = (const char*)Wh + (size_t)(h * 192 + (s - 20) * 16 + lrow) * 512 + wkb + scolb;
            dst = (char*)L + 20480 + (s - 20) * 1024;
        }
        load16(src, dst);
    }
}

__global__ __launch_bounds__(256, 2)
void gru_gemm(const unsigned short* __restrict__ Apl,   // agg planes [N][256]
              const unsigned short* __restrict__ Hcur,  // h planes in  [N][256]
              unsigned short* __restrict__ Hnxt,         // h planes out [N][256]
              const unsigned short* __restrict__ Wi,     // split permuted fused Wih@Wc [384][256]
              const unsigned short* __restrict__ Wh,     // split permuted Whh        [384][256]
              const float* __restrict__ bih, const float* __restrict__ bhh,
              int M, int relu)
{
    __shared__ unsigned short lds[2][16384];  // per buf: A[0,2048) H[2048,4096) Wi[4096,10240) Wh[10240,16384) shorts
    const int t    = threadIdx.x;
    const int lane = t & 63;
    const int wv   = t >> 6;        // 0..3 = wc (col wave)
    const int wc   = wv;
    const int m0   = blockIdx.x * 64;
    const int h    = blockIdx.y;    // column half

    floatx4 arz[2][4], ain[4], ahn[4];
    #pragma unroll
    for (int i = 0; i < 4; ++i) {
        #pragma unroll
        for (int r = 0; r < 4; ++r) {
            arz[0][i][r] = 0.f; arz[1][i][r] = 0.f;
            ain[i][r] = 0.f; ahn[i][r] = 0.f;
        }
    }

    const int lane15 = lane & 15;
    const int quad   = lane >> 4;
    const int sl     = (quad ^ (lane15 & 3)) * 8;   // swizzled 8-short slot (row&3 == lane15&3)

    gg_stage(&lds[0][0], Apl, Hcur, Wi, Wh, wv, lane, m0, M, h, 0);
    __syncthreads();

    int cur = 0;
    for (int kk = 0; kk < 12; ++kk) {
        if (kk < 11) {
            gg_stage(&lds[cur ^ 1][0], Apl, Hcur, Wi, Wh, wv, lane, m0, M, h, kk + 1);
        } else {
            // stage old-h (hold) for the epilogue into lds[0] (free: last read was kk=10)
            #pragma unroll
            for (int j = 0; j < 4; ++j) {
                const int p   = (wv * 4 + j) * 512 + lane * 8;   // short index in E
                const int row = p >> 7;
                const int seg = (lane & 15) * 8;
                int gm = m0 + row; if (gm > M - 1) gm = M - 1;
                const size_t gb = (size_t)gm * 512 +
                    (seg < 64 ? (size_t)(h * 128 + seg * 2) : (size_t)(256 + h * 128 + (seg - 64) * 2));
                load16((const char*)Hcur + gb, (char*)&lds[0][0] + (size_t)p * 2);
            }
        }
        const unsigned short* B = &lds[cur][0];
        short8 a_i[4], a_h[4];
        #pragma unroll
        for (int i = 0; i < 4; ++i) {
            const int ar = i * 16 + lane15;
            a_i[i] = *(const short8*)(B + ar * 32 + sl);
            a_h[i] = *(const short8*)(B + 2048 + ar * 32 + sl);
        }
        #pragma unroll
        for (int j = 0; j < 2; ++j) {
            const int wrow = wc * 48 + j * 16 + lane15;
            const short8 b_i = *(const short8*)(B + 4096 + wrow * 32 + sl);
            const short8 b_h = *(const short8*)(B + 10240 + wrow * 32 + sl);
            #pragma unroll
            for (int i = 0; i < 4; ++i) {
                arz[j][i] = __builtin_amdgcn_mfma_f32_16x16x32_bf16(a_i[i], b_i, arz[j][i], 0, 0, 0);
                arz[j][i] = __builtin_amdgcn_mfma_f32_16x16x32_bf16(a_h[i], b_h, arz[j][i], 0, 0, 0);
            }
        }
        {
            const int wrow = wc * 48 + 32 + lane15;
            const short8 b_i = *(const short8*)(B + 4096 + wrow * 32 + sl);
            const short8 b_h = *(const short8*)(B + 10240 + wrow * 32 + sl);
            #pragma unroll
            for (int i = 0; i < 4; ++i) {
                ain[i] = __builtin_amdgcn_mfma_f32_16x16x32_bf16(a_i[i], b_i, ain[i], 0, 0, 0);
                ahn[i] = __builtin_amdgcn_mfma_f32_16x16x32_bf16(a_h[i], b_h, ahn[i], 0, 0, 0);
            }
        }
        __syncthreads();
        cur ^= 1;
    }

    // ---- epilogue: GRU against LDS-staged hold, coalesced writeback ----
    unsigned short* E = &lds[0][0];            // [64 rows][128 shorts] = hi(64)|lo(64)
    const int cl = wc * 16 + lane15;           // 0..63 local channel
    const int cg = h * 64 + cl;                // global channel
    const float bi0 = bih[cg], bi1 = bih[128 + cg], bi2 = bih[256 + cg];
    const float bh0 = bhh[cg], bh1 = bhh[128 + cg], bh2 = bhh[256 + cg];

    #pragma unroll
    for (int i = 0; i < 4; ++i) {
        #pragma unroll
        for (int r = 0; r < 4; ++r) {
            const int mrow = i * 16 + quad * 4 + r;
            unsigned short* eh = E + mrow * 128 + cl;
            const float hold = bf2f(eh[0]) + bf2f(eh[64]);
            const float rr  = arz[0][i][r] + bi0 + bh0;
            const float zz  = arz[1][i][r] + bi1 + bh1;
            const float in_ = ain[i][r] + bi2;
            const float hn  = ahn[i][r] + bh2;
            const float rg = 1.f / (1.f + __expf(-rr));
            const float zg = 1.f / (1.f + __expf(-zz));
            const float ng = tanhf(in_ + rg * hn);
            float v = (1.f - zg) * ng + zg * hold;
            if (relu) v = fmaxf(v, 0.f);
            unsigned short hi, lo; split2(v, hi, lo);
            eh[0]  = hi;
            eh[64] = lo;
        }
    }
    __syncthreads();

    #pragma unroll
    for (int j = 0; j < 4; ++j) {
        const int p   = (wv * 4 + j) * 512 + lane * 8;
        const int row = p >> 7;
        const int m   = m0 + row;
        if (m < M) {
            const int seg = (lane & 15) * 8;
            const size_t gb = (size_t)m * 512 +
                (seg < 64 ? (size_t)(h * 128 + seg * 2) : (size_t)(256 + h * 128 + (seg - 64) * 2));
            *(ushort8v*)((char*)Hnxt + gb) = *(const ushort8v*)(E + p);
        }
    }
}

// ---------- weight fuse: Wf[l] = Wih @ Wconv[l]  ([384,128] = [384,128]@[128,128]) ----------
__global__ __launch_bounds__(256)
void fuse_w(const float* __restrict__ Wih, const float* __restrict__ Wconv,
            float* __restrict__ Wf)
{
    const int l = blockIdx.y;
    const int o = blockIdx.x * 2 + (threadIdx.x >> 7);
    const int k = threadIdx.x & 127;
    const float* wih = Wih + (size_t)o * 128;
    const float* wcc = Wconv + (size_t)l * 16384 + k;
    float s = 0.f;
    #pragma unroll 8
    for (int j = 0; j < 128; ++j) s += wih[j] * wcc[(size_t)j * 128];
    Wf[(size_t)l * 49152 + (size_t)o * 128 + k] = s;
}

// ---------- splitting: rows of 128 fp32 -> [hi|lo] planes (256 shorts/row) ----------
__global__ __launch_bounds__(256)
void split_act(const float* __restrict__ A, unsigned short* __restrict__ out, int total)
{
    const int tid = blockIdx.x * 256 + threadIdx.x;
    if (tid >= total) return;
    const int n = tid >> 7, k = tid & 127;
    unsigned short hi, lo; split2(A[tid], hi, lo);
    out[(size_t)n * 256 + k]       = hi;
    out[(size_t)n * 256 + 128 + k] = lo;
}

// split with 16-channel gate-interleave row permutation (input [384][128]):
// row o = g*128 + c  ->  op = (c/16)*48 + g*16 + (c%16)
__global__ __launch_bounds__(256)
void split_wt_g(const float* __restrict__ W, unsigned short* __restrict__ out)
{
    const int tid = blockIdx.x * 256 + threadIdx.x;    // over 384*128 exactly
    const int o = tid >> 7, k = tid & 127;
    const int g = o >> 7, c = o & 127;                 // gate, channel
    const int op = (c >> 4) * 48 + g * 16 + (c & 15);  // permuted row
    unsigned short hi, lo; split2(W[tid], hi, lo);
    out[(size_t)op * 256 + k]       = hi;
    out[(size_t)op * 256 + 128 + k] = lo;
}

// ---------- CSR build ----------
__global__ __launch_bounds__(256)
void count_dst(const int* __restrict__ dst, int* __restrict__ counts, int E, int N)
{
    const int e = blockIdx.x * 256 + threadIdx.x;
    if (e >= E) return;
    const int d = dst[e];
    if ((unsigned)d < (unsigned)N) atomicAdd(&counts[d], 1);
}

__global__ __launch_bounds__(256)
void scan_block(const int* __restrict__ counts, int* __restrict__ rowptr,
                int* __restrict__ partials, int N)
{
    __shared__ int sT[256];
    const int t = threadIdx.x;
    const int base = blockIdx.x * SCAN_E + t * 8;
    int v[8]; int s = 0;
    #pragma unroll
    for (int i = 0; i < 8; ++i) {
        const int idx = base + i;
        v[i] = (idx < N) ? counts[idx] : 0;
        s += v[i];
    }
    sT[t] = s;
    __syncthreads();
    for (int off = 1; off < 256; off <<= 1) {
        int x = (t >= off) ? sT[t - off] : 0;
        __syncthreads();
        sT[t] += x;
        __syncthreads();
    }
    if (t == 255) partials[blockIdx.x] = sT[255];
    int run = sT[t] - s;
    #pragma unroll
    for (int i = 0; i < 8; ++i) {
        const int idx = base + i;
        if (idx < N) rowptr[idx] = run;
        run += v[i];
    }
}

__global__ void scan_partials(int* __restrict__ partials, int nb,
                              int* __restrict__ rowptr, int N)
{
    if (threadIdx.x == 0 && blockIdx.x == 0) {
        int run = 0;
        for (int i = 0; i < nb; ++i) { int c = partials[i]; partials[i] = run; run += c; }
        rowptr[N] = run;
    }
}

__global__ __launch_bounds__(256)
void add_offsets(int* __restrict__ rowptr, const int* __restrict__ partials,
                 int* __restrict__ cursor, int N)
{
    const int off  = partials[blockIdx.x];
    const int base = blockIdx.x * SCAN_E + threadIdx.x * 8;
    #pragma unroll
    for (int i = 0; i < 8; ++i) {
        const int idx = base + i;
        if (idx < N) { const int r = rowptr[idx] + off; rowptr[idx] = r; cursor[idx] = r; }
    }
}

__global__ __launch_bounds__(256)
void fill_csr(const int* __restrict__ src, const int* __restrict__ dst,
              int* __restrict__ cursor, int* __restrict__ eidx, int E, int N)
{
    const int e = blockIdx.x * 256 + threadIdx.x;
    if (e >= E) return;
    const int d = dst[e], s = src[e];
    if ((unsigned)d >= (unsigned)N || (unsigned)s >= (unsigned)N) return;
    const int slot = atomicAdd(&cursor[d], 1);
    eidx[slot] = s;
}

// ---------- gather directly on h planes: aggpl = planes(segment_sum(h[src])) ----------
__global__ __launch_bounds__(256)
void gather_sum_h(const unsigned short* __restrict__ hpl, const int* __restrict__ rowptr,
                  const int* __restrict__ eidx, unsigned short* __restrict__ aggpl, int N)
{
    const int tid  = blockIdx.x * 256 + threadIdx.x;
    const int node = tid >> 5;
    const int lane = tid & 31;
    if (node >= N) return;
    const int beg = rowptr[node];
    const int end = rowptr[node + 1];
    float4 acc = make_float4(0.f, 0.f, 0.f, 0.f);
    for (int e = beg; e < end; ++e) {
        const int s = eidx[e];
        const ushort4 vh = *reinterpret_cast<const ushort4*>(hpl + (size_t)s * 256 + lane * 4);
        const ushort4 vl = *reinterpret_cast<const ushort4*>(hpl + (size_t)s * 256 + 128 + lane * 4);
        acc.x += bf2f(vh.x) + bf2f(vl.x);
        acc.y += bf2f(vh.y) + bf2f(vl.y);
        acc.z += bf2f(vh.z) + bf2f(vl.z);
        acc.w += bf2f(vh.w) + bf2f(vl.w);
    }
    ushort4 hi, lo;
    split2(acc.x, hi.x, lo.x); split2(acc.y, hi.y, lo.y);
    split2(acc.z, hi.z, lo.z); split2(acc.w, hi.w, lo.w);
    *reinterpret_cast<ushort4*>(aggpl + (size_t)node * 256 + lane * 4)       = hi;
    *reinterpret_cast<ushort4*>(aggpl + (size_t)node * 256 + 128 + lane * 4) = lo;
}

extern "C" void kernel_launch(void* const* d_in, const int* in_sizes, int n_in,
                              void* d_out, int out_size, void* d_ws, size_t ws_size,
                              hipStream_t stream)
{
    const float* x     = (const float*)d_in[0];
    const int*   edges = (const int*)  d_in[1];
    const float* W1    = (const float*)d_in[2];
    const float* b1    = (const float*)d_in[3];
    const float* Wconv = (const float*)d_in[4];
    const float* Wih   = (const float*)d_in[5];
    const float* Whh   = (const float*)d_in[6];
    const float* bih   = (const float*)d_in[7];
    const float* bhh   = (const float*)d_in[8];
    const float* W2    = (const float*)d_in[9];
    const float* b2    = (const float*)d_in[10];
    float* out = (float*)d_out;

    const int N = in_sizes[0] / D;   // 100000
    const int E = in_sizes[1] / 2;   // 600000

    // ---- workspace layout (~160 MB) ----
    char* base = (char*)d_ws;
    const size_t szH = (size_t)N * 256 * 2;                       // 51.2 MB per plane buffer
    unsigned short* hA     = (unsigned short*)base;
    unsigned short* hB     = (unsigned short*)(base + szH);
    unsigned short* agg_pl = (unsigned short*)(base + 2 * szH);
    char* wb = base + 3 * szH;
    unsigned short* W1s  = (unsigned short*)wb;                   // 128*256
    unsigned short* W2s  = W1s  + (size_t)128 * 256;              // 384*256
    unsigned short* Whhs = W2s  + (size_t)384 * 256;              // 384*256 (permuted)
    unsigned short* Wfs  = Whhs + (size_t)384 * 256;              // 3 * 384*256 (permuted fused)
    float* Wfb = (float*)(Wfs + (size_t)3 * 384 * 256);           // 3*384*128 fp32 temp
    int* rowptr   = (int*)((char*)Wfb + (size_t)3 * 384 * 128 * 4);
    int* counts   = rowptr + N + 1;                               // doubles as cursor
    int* partials = counts + N;
    int* eidx     = partials + 64;
    unsigned short* x_pl = agg_pl;   // alias: x planes dead before first gather writes agg

    const int* src = edges;
    const int* dst = edges + E;

    const dim3 blk(256);
    const int mb   = (N + 127) / 128;               // 782
    const int mb64 = (N + 63) / 64;                 // 1563
    const int nb = (N + SCAN_E - 1) / SCAN_E;

    // ---- weight prep ----
    split_act<<<dim3(64),  blk, 0, stream>>>(W1, W1s, 128 * 128);
    split_act<<<dim3(192), blk, 0, stream>>>(W2, W2s, 384 * 128);
    fuse_w<<<dim3(192, 3), blk, 0, stream>>>(Wih, Wconv, Wfb);
    for (int l = 0; l < 3; ++l)
        split_wt_g<<<dim3(192), blk, 0, stream>>>(Wfb + (size_t)l * 49152,
                                                  Wfs + (size_t)l * 98304);
    split_wt_g<<<dim3(192), blk, 0, stream>>>(Whh, Whhs);
    split_act<<<dim3((N * 128 + 255) / 256), blk, 0, stream>>>(x, x_pl, N * 128);

    // ---- build CSR (dst-bucketed) once ----
    hipMemsetAsync(counts, 0, (size_t)N * sizeof(int), stream);
    count_dst<<<dim3((E + 255) / 256), blk, 0, stream>>>(dst, counts, E, N);
    scan_block<<<dim3(nb), blk, 0, stream>>>(counts, rowptr, partials, N);
    scan_partials<<<dim3(1), dim3(64), 0, stream>>>(partials, nb, rowptr, N);
    add_offsets<<<dim3(nb), blk, 0, stream>>>(rowptr, partials, counts, N);
    fill_csr<<<dim3((E + 255) / 256), blk, 0, stream>>>(src, dst, counts, eidx, E, N);

    // ---- h = relu(x @ W1^T + b1), stored as planes only ----
    gemm_split<<<dim3(mb, 1), blk, 0, stream>>>(x_pl, W1s, b1, nullptr, hA, N, 128, 1);

    // ---- layers: gather(h) then fused dual-GEMM + GRU (ping-pong h) ----
    unsigned short* hcur = hA;
    unsigned short* hnxt = hB;
    for (int l = 0; l < 3; ++l) {
        gather_sum_h<<<dim3((N * 32 + 255) / 256), blk, 0, stream>>>(hcur, rowptr, eidx, agg_pl, N);
        gru_gemm<<<dim3(mb64, 2), blk, 0, stream>>>(agg_pl, hcur, hnxt,
                                                    Wfs + (size_t)l * 98304, Whhs,
                                                    bih, bhh, N, l == 2);
        unsigned short* tmp = hcur; hcur = hnxt; hnxt = tmp;
    }

    // ---- out = relu(h) @ W2^T + b2 (relu already applied in planes) ----
    gemm_split<<<dim3(mb, 3), blk, 0, stream>>>(hcur, W2s, b2, out, nullptr, N, 384, 0);
}

// Round 5
// 862.193 us; speedup vs baseline: 1.5233x; 1.1068x over previous
//
#include <hip/hip_runtime.h>

#define D 128
#define SCAN_E 2048

typedef __attribute__((ext_vector_type(8))) short short8;
typedef __attribute__((ext_vector_type(8))) unsigned short ushort8v;
typedef __attribute__((ext_vector_type(4))) float floatx4;

__device__ __forceinline__ unsigned short f2bf(float x) {
    union { float f; unsigned u; } v; v.f = x;
    unsigned r = v.u + 0x7FFFu + ((v.u >> 16) & 1u);
    return (unsigned short)(r >> 16);
}
__device__ __forceinline__ float bf2f(unsigned short h) {
    union { float f; unsigned u; } v; v.u = ((unsigned)h) << 16;
    return v.f;
}
__device__ __forceinline__ void split2(float x, unsigned short& hi, unsigned short& lo) {
    hi = f2bf(x);
    lo = f2bf(x - bf2f(hi));
}
// NOTE: the 4th intrinsic arg (imm offset) applies to BOTH global and LDS addresses —
// never use it for global-only offsets; fold offsets into the global pointer instead.
__device__ __forceinline__ void load16(const void* g, void* l) {
    __builtin_amdgcn_global_load_lds((const __attribute__((address_space(1))) unsigned*)g,
                                     (__attribute__((address_space(3))) unsigned*)l, 16, 0, 0);
}

// ---------- split-precision bf16 MFMA GEMM ----------
// C[M,NC] = A @ W^T (+bias); A as bf16 planes [M][256] = [Ah|Al], W as [NC][256] = [Wh|Wl].
// Effective K=384 bf16: Ah*Wh ; Al*Wh ; Ah*Wl  (error <= 2^-17).
// 128-B LDS rows: XOR swizzle c^=(r&7) is conflict-free (octet-distinct).
__global__ __launch_bounds__(256, 2)
void gemm_split(const unsigned short* __restrict__ Apl,
                const unsigned short* __restrict__ Wsp,
                const float* __restrict__ bias,
                float* __restrict__ Cf,            // fp32 out (or null)
                unsigned short* __restrict__ Cpl,  // bf16-plane out [M][256] (or null; NC==128 only)
                int M, int NC, int relu)
{
    __shared__ unsigned short sA[128 * 64];
    __shared__ unsigned short sW[128 * 64];
    const int t    = threadIdx.x;
    const int lane = t & 63;
    const int wv   = t >> 6;
    const int m0   = blockIdx.x * 128;
    const int n0   = blockIdx.y * 128;

    const int lrow  = lane >> 3;                         // 0..7
    const int scolb = (((lane & 7) ^ (lrow & 7)) << 4);  // pre-swizzled 16-B slot

    floatx4 acc[4][4];
    #pragma unroll
    for (int i = 0; i < 4; ++i)
        #pragma unroll
        for (int j = 0; j < 4; ++j)
            #pragma unroll
            for (int r = 0; r < 4; ++r) acc[i][j][r] = 0.f;

    for (int kk = 0; kk < 6; ++kk) {
        const int akb = ((kk < 4) ? kk : kk - 4) * 128;  // A row = 512 B: Ah,Al,Ah
        const int wkb = ((kk < 2) ? kk : kk - 2) * 128;  // W row = 512 B: Wh,Wh,Wl
        #pragma unroll
        for (int i = 0; i < 4; ++i) {
            const int rr = (wv * 4 + i) * 8 + lrow;      // 0..127 tile row
            int am = m0 + rr; if (am > M - 1) am = M - 1;
            load16((const char*)Apl + (size_t)am * 512 + akb + scolb,
                   (char*)sA + (size_t)(wv * 4 + i) * 1024);
            load16((const char*)Wsp + (size_t)(n0 + rr) * 512 + wkb + scolb,
                   (char*)sW + (size_t)(wv * 4 + i) * 1024);
        }
        __syncthreads();
        const int lane15 = lane & 15;
        const int quad   = lane >> 4;
        const int r7     = lane15 & 7;
        #pragma unroll
        for (int ks = 0; ks < 2; ++ks) {
            short8 a[4], b[4];
            const int sl = ((ks * 4 + quad) ^ r7) * 8;   // swizzled 8-short slot
            #pragma unroll
            for (int i = 0; i < 4; ++i)
                a[i] = *(const short8*)(sA + ((wv >> 1) * 64 + i * 16 + lane15) * 64 + sl);
            #pragma unroll
            for (int j = 0; j < 4; ++j)
                b[j] = *(const short8*)(sW + ((wv & 1) * 64 + j * 16 + lane15) * 64 + sl);
            #pragma unroll
            for (int i = 0; i < 4; ++i)
                #pragma unroll
                for (int j = 0; j < 4; ++j)
                    acc[i][j] = __builtin_amdgcn_mfma_f32_16x16x32_bf16(a[i], b[j], acc[i][j], 0, 0, 0);
        }
        __syncthreads();
    }

    const int lane15 = lane & 15;
    const int quad   = lane >> 4;
    #pragma unroll
    for (int i = 0; i < 4; ++i) {
        #pragma unroll
        for (int r = 0; r < 4; ++r) {
            const int m = m0 + (wv >> 1) * 64 + i * 16 + quad * 4 + r;
            if (m >= M) continue;
            #pragma unroll
            for (int j = 0; j < 4; ++j) {
                const int n = n0 + (wv & 1) * 64 + j * 16 + lane15;
                float v = acc[i][j][r] + (bias ? bias[n] : 0.f);
                if (relu) v = fmaxf(v, 0.f);
                if (Cf) Cf[(size_t)m * NC + n] = v;
                if (Cpl) {
                    unsigned short hi, lo; split2(v, hi, lo);
                    Cpl[(size_t)m * 256 + n] = hi;
                    Cpl[(size_t)m * 256 + 128 + n] = lo;
                }
            }
        }
    }
}

// ---------- fused dual-GEMM + GRU v5 ----------
// grid (ceil(N/64), 2); 256 thr; 64 rows x 64 channels (col-half h).
// 8 chunks: 0-3 stage {Ah,Al,Hh,Hl}+{Wi_hi,Wh_hi} -> 48 MFMA/wave;
//           4-7 stage {Ah,Hh}+{Wi_lo,Wh_lo} -> 24 MFMA/wave.  (Wh plane staged ONCE.)
// Per-lane source row base ptrs precomputed once; chunk offset = runtime pointer add
// (NOT the builtin imm offset — that is added to BOTH global and LDS addresses).
// LDS swizzle for 64-B rows: slot c ^= (row>>1)&3 (octet-distinct bank quads).
// LDS per buf (shorts): Ah 0 | Al 2048 | Hh 4096 | Hl 6144 | Wi 8192 | Wh 14336. 2x40 KB.
template<int P>
__device__ __forceinline__ void gg_stage(char* L, int wv,
    const char* const (&ab)[4], const char* const (&wp)[12])
{
    constexpr int ahi = (P < 4 ? P : P - 4) * 64;
    constexpr int alo = 256 + (P < 4 ? P : 0) * 64;
    constexpr int wof = (P < 4) ? P * 64 : 256 + (P - 4) * 64;
    if (wv < 2) {
        char* dst = L + (wv ? 8192 : 0);
        #pragma unroll
        for (int i = 0; i < 4; ++i) {
            load16(ab[i] + ahi, dst + i * 1024);
            if constexpr (P < 4) load16(ab[i] + alo, dst + 4096 + i * 1024);
        }
    } else {
        char* dst = L + (wv == 2 ? 16384 : 28672);
        #pragma unroll
        for (int j = 0; j < 12; ++j)
            load16(wp[j] + wof, dst + j * 1024);
    }
}

template<bool FULL>
__device__ __forceinline__ void gg_compute(const unsigned short* B, int lane15, int sl, int wc,
    floatx4 (&arz)[2][4], floatx4 (&ain)[4], floatx4 (&ahn)[4])
{
    short8 ah[4], hh[4], al[4], hl[4];
    #pragma unroll
    for (int i = 0; i < 4; ++i) {
        const int ar = (i * 16 + lane15) * 32;
        ah[i] = *(const short8*)(B + ar + sl);
        hh[i] = *(const short8*)(B + 4096 + ar + sl);
        if constexpr (FULL) {
            al[i] = *(const short8*)(B + 2048 + ar + sl);
            hl[i] = *(const short8*)(B + 6144 + ar + sl);
        }
    }
    #pragma unroll
    for (int j = 0; j < 2; ++j) {
        const int wr = (wc * 48 + j * 16 + lane15) * 32;
        const short8 bi = *(const short8*)(B + 8192 + wr + sl);
        const short8 bh = *(const short8*)(B + 14336 + wr + sl);
        #pragma unroll
        for (int i = 0; i < 4; ++i) {
            arz[j][i] = __builtin_amdgcn_mfma_f32_16x16x32_bf16(ah[i], bi, arz[j][i], 0, 0, 0);
            arz[j][i] = __builtin_amdgcn_mfma_f32_16x16x32_bf16(hh[i], bh, arz[j][i], 0, 0, 0);
            if constexpr (FULL) {
                arz[j][i] = __builtin_amdgcn_mfma_f32_16x16x32_bf16(al[i], bi, arz[j][i], 0, 0, 0);
                arz[j][i] = __builtin_amdgcn_mfma_f32_16x16x32_bf16(hl[i], bh, arz[j][i], 0, 0, 0);
            }
        }
    }
    {
        const int wr = (wc * 48 + 32 + lane15) * 32;
        const short8 bi = *(const short8*)(B + 8192 + wr + sl);
        const short8 bh = *(const short8*)(B + 14336 + wr + sl);
        #pragma unroll
        for (int i = 0; i < 4; ++i) {
            ain[i] = __builtin_amdgcn_mfma_f32_16x16x32_bf16(ah[i], bi, ain[i], 0, 0, 0);
            ahn[i] = __builtin_amdgcn_mfma_f32_16x16x32_bf16(hh[i], bh, ahn[i], 0, 0, 0);
            if constexpr (FULL) {
                ain[i] = __builtin_amdgcn_mfma_f32_16x16x32_bf16(al[i], bi, ain[i], 0, 0, 0);
                ahn[i] = __builtin_amdgcn_mfma_f32_16x16x32_bf16(hl[i], bh, ahn[i], 0, 0, 0);
            }
        }
    }
}

__device__ __forceinline__ void hold_stage(char* L0, const unsigned short* Hcur,
                                           int wv, int lane, int m0, int M, int h)
{
    #pragma unroll
    for (int j = 0; j < 4; ++j) {
        const int p   = (wv * 4 + j) * 512 + lane * 8;   // short index in E
        const int row = p >> 7;
        const int seg = (lane & 15) * 8;
        int gm = m0 + row; if (gm > M - 1) gm = M - 1;
        const size_t gb = (size_t)gm * 512 +
            (seg < 64 ? (size_t)(h * 128 + seg * 2) : (size_t)(256 + h * 128 + (seg - 64) * 2));
        load16((const char*)Hcur + gb, L0 + (size_t)p * 2);
    }
}

__global__ __launch_bounds__(256, 2)
void gru_gemm(const unsigned short* __restrict__ Apl,   // agg planes [N][256]
              const unsigned short* __restrict__ Hcur,  // h planes in  [N][256]
              unsigned short* __restrict__ Hnxt,         // h planes out [N][256]
              const unsigned short* __restrict__ Wi,     // split permuted fused Wih@Wc [384][256]
              const unsigned short* __restrict__ Wh,     // split permuted Whh        [384][256]
              const float* __restrict__ bih, const float* __restrict__ bhh,
              int M, int relu)
{
    __shared__ unsigned short lds[2][20480];   // 2 x 40 KB
    const int t    = threadIdx.x;
    const int lane = t & 63;
    const int wv   = t >> 6;        // 0..3 = wc (col wave)
    const int wc   = wv;
    const int m0   = blockIdx.x * 64;
    const int h    = blockIdx.y;    // column half

    const int lrow  = lane >> 2;                                // 0..15
    const int scolb = (((lane & 3) ^ ((lrow >> 1) & 3)) << 4);  // 64-B-row swizzle

    // per-lane source row base pointers (computed once)
    const char* ab[4];
    const char* wp[12];
    if (wv < 2) {
        const char* srcp = wv ? (const char*)Hcur : (const char*)Apl;
        #pragma unroll
        for (int i = 0; i < 4; ++i) {
            int am = m0 + i * 16 + lrow; if (am > M - 1) am = M - 1;
            ab[i] = srcp + (size_t)am * 512 + scolb;
        }
        #pragma unroll
        for (int j = 0; j < 12; ++j) wp[j] = srcp;
    } else {
        const char* srcp = (wv == 2) ? (const char*)Wi : (const char*)Wh;
        #pragma unroll
        for (int j = 0; j < 12; ++j)
            wp[j] = srcp + (size_t)(h * 192 + j * 16 + lrow) * 512 + scolb;
        #pragma unroll
        for (int i = 0; i < 4; ++i) ab[i] = srcp;
    }

    floatx4 arz[2][4], ain[4], ahn[4];
    #pragma unroll
    for (int i = 0; i < 4; ++i)
        #pragma unroll
        for (int r = 0; r < 4; ++r) {
            arz[0][i][r] = 0.f; arz[1][i][r] = 0.f;
            ain[i][r] = 0.f; ahn[i][r] = 0.f;
        }

    const int lane15 = lane & 15;
    const int quad   = lane >> 4;
    const int sl     = ((quad ^ ((lane15 >> 1) & 3)) << 3);  // swizzled 8-short slot

    char* L0 = (char*)&lds[0][0];
    char* L1 = (char*)&lds[1][0];
    const unsigned short* B0 = &lds[0][0];
    const unsigned short* B1 = &lds[1][0];

    gg_stage<0>(L0, wv, ab, wp);
    __syncthreads();
    gg_stage<1>(L1, wv, ab, wp);  gg_compute<true >(B0, lane15, sl, wc, arz, ain, ahn); __syncthreads();
    gg_stage<2>(L0, wv, ab, wp);  gg_compute<true >(B1, lane15, sl, wc, arz, ain, ahn); __syncthreads();
    gg_stage<3>(L1, wv, ab, wp);  gg_compute<true >(B0, lane15, sl, wc, arz, ain, ahn); __syncthreads();
    gg_stage<4>(L0, wv, ab, wp);  gg_compute<true >(B1, lane15, sl, wc, arz, ain, ahn); __syncthreads();
    gg_stage<5>(L1, wv, ab, wp);  gg_compute<false>(B0, lane15, sl, wc, arz, ain, ahn); __syncthreads();
    gg_stage<6>(L0, wv, ab, wp);  gg_compute<false>(B1, lane15, sl, wc, arz, ain, ahn); __syncthreads();
    gg_stage<7>(L1, wv, ab, wp);  gg_compute<false>(B0, lane15, sl, wc, arz, ain, ahn); __syncthreads();
    hold_stage(L0, Hcur, wv, lane, m0, M, h);
    gg_compute<false>(B1, lane15, sl, wc, arz, ain, ahn);
    __syncthreads();

    // ---- epilogue: GRU against LDS-staged hold, coalesced writeback ----
    unsigned short* E = &lds[0][0];            // [64 rows][128 shorts] = hi(64)|lo(64)
    const int cl = wc * 16 + lane15;           // 0..63 local channel
    const int cg = h * 64 + cl;                // global channel
    const float bi0 = bih[cg], bi1 = bih[128 + cg], bi2 = bih[256 + cg];
    const float bh0 = bhh[cg], bh1 = bhh[128 + cg], bh2 = bhh[256 + cg];

    #pragma unroll
    for (int i = 0; i < 4; ++i) {
        #pragma unroll
        for (int r = 0; r < 4; ++r) {
            const int mrow = i * 16 + quad * 4 + r;
            unsigned short* eh = E + mrow * 128 + cl;
            const float hold = bf2f(eh[0]) + bf2f(eh[64]);
            const float rr  = arz[0][i][r] + bi0 + bh0;
            const float zz  = arz[1][i][r] + bi1 + bh1;
            const float in_ = ain[i][r] + bi2;
            const float hn  = ahn[i][r] + bh2;
            const float rg = 1.f / (1.f + __expf(-rr));
            const float zg = 1.f / (1.f + __expf(-zz));
            const float ng = tanhf(in_ + rg * hn);
            float v = (1.f - zg) * ng + zg * hold;
            if (relu) v = fmaxf(v, 0.f);
            unsigned short hi, lo; split2(v, hi, lo);
            eh[0]  = hi;
            eh[64] = lo;
        }
    }
    __syncthreads();

    #pragma unroll
    for (int j = 0; j < 4; ++j) {
        const int p   = (wv * 4 + j) * 512 + lane * 8;
        const int row = p >> 7;
        const int m   = m0 + row;
        if (m < M) {
            const int seg = (lane & 15) * 8;
            const size_t gb = (size_t)m * 512 +
                (seg < 64 ? (size_t)(h * 128 + seg * 2) : (size_t)(256 + h * 128 + (seg - 64) * 2));
            *(ushort8v*)((char*)Hnxt + gb) = *(const ushort8v*)(E + p);
        }
    }
}

// ---------- weight fuse: Wf[l] = Wih @ Wconv[l]  ([384,128] = [384,128]@[128,128]) ----------
__global__ __launch_bounds__(256)
void fuse_w(const float* __restrict__ Wih, const float* __restrict__ Wconv,
            float* __restrict__ Wf)
{
    const int l = blockIdx.y;
    const int o = blockIdx.x * 2 + (threadIdx.x >> 7);
    const int k = threadIdx.x & 127;
    const float* wih = Wih + (size_t)o * 128;
    const float* wcc = Wconv + (size_t)l * 16384 + k;
    float s = 0.f;
    #pragma unroll 8
    for (int j = 0; j < 128; ++j) s += wih[j] * wcc[(size_t)j * 128];
    Wf[(size_t)l * 49152 + (size_t)o * 128 + k] = s;
}

// ---------- splitting: rows of 128 fp32 -> [hi|lo] planes (256 shorts/row) ----------
__global__ __launch_bounds__(256)
void split_act(const float* __restrict__ A, unsigned short* __restrict__ out, int total)
{
    const int tid = blockIdx.x * 256 + threadIdx.x;
    if (tid >= total) return;
    const int n = tid >> 7, k = tid & 127;
    unsigned short hi, lo; split2(A[tid], hi, lo);
    out[(size_t)n * 256 + k]       = hi;
    out[(size_t)n * 256 + 128 + k] = lo;
}

// split with 16-channel gate-interleave row permutation (input [384][128]):
// row o = g*128 + c  ->  op = (c/16)*48 + g*16 + (c%16)
__global__ __launch_bounds__(256)
void split_wt_g(const float* __restrict__ W, unsigned short* __restrict__ out)
{
    const int tid = blockIdx.x * 256 + threadIdx.x;    // over 384*128 exactly
    const int o = tid >> 7, k = tid & 127;
    const int g = o >> 7, c = o & 127;                 // gate, channel
    const int op = (c >> 4) * 48 + g * 16 + (c & 15);  // permuted row
    unsigned short hi, lo; split2(W[tid], hi, lo);
    out[(size_t)op * 256 + k]       = hi;
    out[(size_t)op * 256 + 128 + k] = lo;
}

// ---------- CSR build ----------
__global__ __launch_bounds__(256)
void count_dst(const int* __restrict__ dst, int* __restrict__ counts, int E, int N)
{
    const int e = blockIdx.x * 256 + threadIdx.x;
    if (e >= E) return;
    const int d = dst[e];
    if ((unsigned)d < (unsigned)N) atomicAdd(&counts[d], 1);
}

__global__ __launch_bounds__(256)
void scan_block(const int* __restrict__ counts, int* __restrict__ rowptr,
                int* __restrict__ partials, int N)
{
    __shared__ int sT[256];
    const int t = threadIdx.x;
    const int base = blockIdx.x * SCAN_E + t * 8;
    int v[8]; int s = 0;
    #pragma unroll
    for (int i = 0; i < 8; ++i) {
        const int idx = base + i;
        v[i] = (idx < N) ? counts[idx] : 0;
        s += v[i];
    }
    sT[t] = s;
    __syncthreads();
    for (int off = 1; off < 256; off <<= 1) {
        int x = (t >= off) ? sT[t - off] : 0;
        __syncthreads();
        sT[t] += x;
        __syncthreads();
    }
    if (t == 255) partials[blockIdx.x] = sT[255];
    int run = sT[t] - s;
    #pragma unroll
    for (int i = 0; i < 8; ++i) {
        const int idx = base + i;
        if (idx < N) rowptr[idx] = run;
        run += v[i];
    }
}

__global__ void scan_partials(int* __restrict__ partials, int nb,
                              int* __restrict__ rowptr, int N)
{
    if (threadIdx.x == 0 && blockIdx.x == 0) {
        int run = 0;
        for (int i = 0; i < nb; ++i) { int c = partials[i]; partials[i] = run; run += c; }
        rowptr[N] = run;
    }
}

__global__ __launch_bounds__(256)
void add_offsets(int* __restrict__ rowptr, const int* __restrict__ partials,
                 int* __restrict__ cursor, int N)
{
    const int off  = partials[blockIdx.x];
    const int base = blockIdx.x * SCAN_E + threadIdx.x * 8;
    #pragma unroll
    for (int i = 0; i < 8; ++i) {
        const int idx = base + i;
        if (idx < N) { const int r = rowptr[idx] + off; rowptr[idx] = r; cursor[idx] = r; }
    }
}

__global__ __launch_bounds__(256)
void fill_csr(const int* __restrict__ src, const int* __restrict__ dst,
              int* __restrict__ cursor, int* __restrict__ eidx, int E, int N)
{
    const int e = blockIdx.x * 256 + threadIdx.x;
    if (e >= E) return;
    const int d = dst[e], s = src[e];
    if ((unsigned)d >= (unsigned)N || (unsigned)s >= (unsigned)N) return;
    const int slot = atomicAdd(&cursor[d], 1);
    eidx[slot] = s;
}

// ---------- gather: aggpl = planes(segment_sum(h[src])) ----------
// 32 lanes/node; each lane one 16-B load per edge (lanes 0-15 hi plane, 16-31 lo);
// 2-edge unroll; shfl_down(16) hi+lo combine.
__global__ __launch_bounds__(256)
void gather_sum_h(const unsigned short* __restrict__ hpl, const int* __restrict__ rowptr,
                  const int* __restrict__ eidx, unsigned short* __restrict__ aggpl, int N)
{
    const int tid  = blockIdx.x * 256 + threadIdx.x;
    const int node = tid >> 5;
    const int lane = tid & 31;
    if (node >= N) return;
    const int beg = rowptr[node];
    const int end = rowptr[node + 1];
    float acc[8];
    #pragma unroll
    for (int c = 0; c < 8; ++c) acc[c] = 0.f;
    int e = beg;
    for (; e + 2 <= end; e += 2) {
        const int s0 = eidx[e], s1 = eidx[e + 1];
        const ushort8v v0 = *(const ushort8v*)(hpl + (size_t)s0 * 256 + lane * 8);
        const ushort8v v1 = *(const ushort8v*)(hpl + (size_t)s1 * 256 + lane * 8);
        #pragma unroll
        for (int c = 0; c < 8; ++c) acc[c] += bf2f(v0[c]) + bf2f(v1[c]);
    }
    if (e < end) {
        const int s0 = eidx[e];
        const ushort8v v0 = *(const ushort8v*)(hpl + (size_t)s0 * 256 + lane * 8);
        #pragma unroll
        for (int c = 0; c < 8; ++c) acc[c] += bf2f(v0[c]);
    }
    #pragma unroll
    for (int c = 0; c < 8; ++c) acc[c] += __shfl_down(acc[c], 16);
    if (lane < 16) {
        ushort8v hi8, lo8;
        #pragma unroll
        for (int c = 0; c < 8; ++c) {
            unsigned short hi, lo; split2(acc[c], hi, lo);
            hi8[c] = hi; lo8[c] = lo;
        }
        *(ushort8v*)(aggpl + (size_t)node * 256 + lane * 8)       = hi8;
        *(ushort8v*)(aggpl + (size_t)node * 256 + 128 + lane * 8) = lo8;
    }
}

extern "C" void kernel_launch(void* const* d_in, const int* in_sizes, int n_in,
                              void* d_out, int out_size, void* d_ws, size_t ws_size,
                              hipStream_t stream)
{
    const float* x     = (const float*)d_in[0];
    const int*   edges = (const int*)  d_in[1];
    const float* W1    = (const float*)d_in[2];
    const float* b1    = (const float*)d_in[3];
    const float* Wconv = (const float*)d_in[4];
    const float* Wih   = (const float*)d_in[5];
    const float* Whh   = (const float*)d_in[6];
    const float* bih   = (const float*)d_in[7];
    const float* bhh   = (const float*)d_in[8];
    const float* W2    = (const float*)d_in[9];
    const float* b2    = (const float*)d_in[10];
    float* out = (float*)d_out;

    const int N = in_sizes[0] / D;   // 100000
    const int E = in_sizes[1] / 2;   // 600000

    // ---- workspace layout (~160 MB) ----
    char* base = (char*)d_ws;
    const size_t szH = (size_t)N * 256 * 2;                       // 51.2 MB per plane buffer
    unsigned short* hA     = (unsigned short*)base;
    unsigned short* hB     = (unsigned short*)(base + szH);
    unsigned short* agg_pl = (unsigned short*)(base + 2 * szH);
    char* wb = base + 3 * szH;
    unsigned short* W1s  = (unsigned short*)wb;                   // 128*256
    unsigned short* W2s  = W1s  + (size_t)128 * 256;              // 384*256
    unsigned short* Whhs = W2s  + (size_t)384 * 256;              // 384*256 (permuted)
    unsigned short* Wfs  = Whhs + (size_t)384 * 256;              // 3 * 384*256 (permuted fused)
    float* Wfb = (float*)(Wfs + (size_t)3 * 384 * 256);           // 3*384*128 fp32 temp
    int* rowptr   = (int*)((char*)Wfb + (size_t)3 * 384 * 128 * 4);
    int* counts   = rowptr + N + 1;                               // doubles as cursor
    int* partials = counts + N;
    int* eidx     = partials + 64;
    unsigned short* x_pl = agg_pl;   // alias: x planes dead before first gather writes agg

    const int* src = edges;
    const int* dst = edges + E;

    const dim3 blk(256);
    const int mb   = (N + 127) / 128;               // 782
    const int mb64 = (N + 63) / 64;                 // 1563
    const int nb = (N + SCAN_E - 1) / SCAN_E;

    // ---- weight prep ----
    split_act<<<dim3(64),  blk, 0, stream>>>(W1, W1s, 128 * 128);
    split_act<<<dim3(192), blk, 0, stream>>>(W2, W2s, 384 * 128);
    fuse_w<<<dim3(192, 3), blk, 0, stream>>>(Wih, Wconv, Wfb);
    for (int l = 0; l < 3; ++l)
        split_wt_g<<<dim3(192), blk, 0, stream>>>(Wfb + (size_t)l * 49152,
                                                  Wfs + (size_t)l * 98304);
    split_wt_g<<<dim3(192), blk, 0, stream>>>(Whh, Whhs);
    split_act<<<dim3((N * 128 + 255) / 256), blk, 0, stream>>>(x, x_pl, N * 128);

    // ---- build CSR (dst-bucketed) once ----
    hipMemsetAsync(counts, 0, (size_t)N * sizeof(int), stream);
    count_dst<<<dim3((E + 255) / 256), blk, 0, stream>>>(dst, counts, E, N);
    scan_block<<<dim3(nb), blk, 0, stream>>>(counts, rowptr, partials, N);
    scan_partials<<<dim3(1), dim3(64), 0, stream>>>(partials, nb, rowptr, N);
    add_offsets<<<dim3(nb), blk, 0, stream>>>(rowptr, partials, counts, N);
    fill_csr<<<dim3((E + 255) / 256), blk, 0, stream>>>(src, dst, counts, eidx, E, N);

    // ---- h = relu(x @ W1^T + b1), stored as planes only ----
    gemm_split<<<dim3(mb, 1), blk, 0, stream>>>(x_pl, W1s, b1, nullptr, hA, N, 128, 1);

    // ---- layers: gather(h) then fused dual-GEMM + GRU (ping-pong h) ----
    unsigned short* hcur = hA;
    unsigned short* hnxt = hB;
    for (int l = 0; l < 3; ++l) {
        gather_sum_h<<<dim3((N * 32 + 255) / 256), blk, 0, stream>>>(hcur, rowptr, eidx, agg_pl, N);
        gru_gemm<<<dim3(mb64, 2), blk, 0, stream>>>(agg_pl, hcur, hnxt,
                                                    Wfs + (size_t)l * 98304, Whhs,
                                                    bih, bhh, N, l == 2);
        unsigned short* tmp = hcur; hcur = hnxt; hnxt = tmp;
    }

    // ---- out = relu(h) @ W2^T + b2 (relu already applied in planes) ----
    gemm_split<<<dim3(mb, 3), blk, 0, stream>>>(hcur, W2s, b2, out, nullptr, N, 384, 0);
}